// Round 1
// baseline (10528.849 us; speedup 1.0000x reference)
//
#include <hip/hip_runtime.h>

// OrthogonalTransform: out = (H_0 H_1 ... H_{m-1}) x^T, transposed back.
// U = triu(weight), U[n-1][n-1] = 1.0. Reflections applied i = n-1 .. 0.
// H_i: h <- h - (2/||u_i||^2) u_i (u_i^T h), skipped when ||u_i||^2 == 0.
//
// Strategy (round 0): wave-autonomous, register-resident h.
//  - Each wave owns VC=2 batch columns for the whole kernel.
//  - Lane owns rows {lane + 64k : k=0..31} (strided -> triangular work balanced).
//  - Per reflection: masked coalesced load of weight row i, fused dots
//    (u.u, u.h0, u.h1), one 64-lane butterfly reduce, rank-1 update.
//  - No LDS, no barriers, no inter-block deps.

#define N_DIM 2048
#define NR 32                 // rows per lane = N_DIM / 64
#define VC 2                  // batch columns per wave
#define WAVES_PER_BLOCK 4
#define THREADS (WAVES_PER_BLOCK * 64)

__global__ __launch_bounds__(THREADS, 2)
void OrthogonalTransform_house_kernel(const float* __restrict__ x,
                                      const float* __restrict__ w,
                                      float* __restrict__ out) {
  const int lane = threadIdx.x & 63;
  const int wave = threadIdx.x >> 6;
  const int gw   = blockIdx.x * WAVES_PER_BLOCK + wave;
  const int col0 = gw * VC;   // batch indices handled by this wave

  // h[k][c] = x[col0+c][lane + 64k]   (h = x^T, column-per-batch)
  float h[NR][VC];
#pragma unroll
  for (int k = 0; k < NR; ++k) {
    const int r = lane + 64 * k;
#pragma unroll
    for (int c = 0; c < VC; ++c)
      h[k][c] = x[(size_t)(col0 + c) * N_DIM + r];
  }

  // Reflection i = N-1: u = e_{N-1} (U[-1,-1]=1), coef = 2 -> negate row N-1.
  if (lane == 63) {
#pragma unroll
    for (int c = 0; c < VC; ++c) h[NR - 1][c] = -h[NR - 1][c];
  }

  // Reflections i = N-2 .. 0
  for (int i = N_DIM - 2; i >= 0; --i) {
    const float* wrow = w + (size_t)i * N_DIM;
    float uk[NR];
    float n2 = 0.f, d0 = 0.f, d1 = 0.f;

#pragma unroll
    for (int k = 0; k < NR; ++k) {
      if (64 * k + 63 >= i) {          // wave-uniform skip of dead k-blocks
        const int r = lane + 64 * k;
        float u = wrow[r];             // coalesced; lower-tri load masked below
        u = (r >= i) ? u : 0.f;
        uk[k] = u;
        n2 = fmaf(u, u, n2);
        d0 = fmaf(u, h[k][0], d0);
        d1 = fmaf(u, h[k][1], d1);
      }
    }

    // 64-lane butterfly reduce (all lanes get the sums)
#pragma unroll
    for (int m = 1; m < 64; m <<= 1) {
      n2 += __shfl_xor(n2, m, 64);
      d0 += __shfl_xor(d0, m, 64);
      d1 += __shfl_xor(d1, m, 64);
    }

    const float cf = (n2 > 0.f) ? 2.0f / n2 : 0.f;
    const float s0 = cf * d0;
    const float s1 = cf * d1;

#pragma unroll
    for (int k = 0; k < NR; ++k) {
      if (64 * k + 63 >= i) {
        h[k][0] = fmaf(-uk[k], s0, h[k][0]);
        h[k][1] = fmaf(-uk[k], s1, h[k][1]);
      }
    }
  }

  // out[b][r] = h[r][b]
#pragma unroll
  for (int k = 0; k < NR; ++k) {
    const int r = lane + 64 * k;
#pragma unroll
    for (int c = 0; c < VC; ++c)
      out[(size_t)(col0 + c) * N_DIM + r] = h[k][c];
  }
}

extern "C" void kernel_launch(void* const* d_in, const int* in_sizes, int n_in,
                              void* d_out, int out_size, void* d_ws, size_t ws_size,
                              hipStream_t stream) {
  const float* x = (const float*)d_in[0];   // (B, N) f32
  const float* w = (const float*)d_in[1];   // (N, M) f32
  float* out = (float*)d_out;               // (B, N) f32

  const int B = in_sizes[0] / N_DIM;        // 4096
  const int grid = B / (VC * WAVES_PER_BLOCK); // 512 blocks -> 2048 waves

  OrthogonalTransform_house_kernel<<<grid, THREADS, 0, stream>>>(x, w, out);
}

// Round 2
// 5645.787 us; speedup vs baseline: 1.8649x; 1.8649x over previous
//
#include <hip/hip_runtime.h>

// OrthogonalTransform via in-register blocked Householder (compact WY).
// U = triu(weight), U[n-1][n-1] = 1.0; apply H_i for i = n-1 .. 0 to h = x^T.
// Group K=8 consecutive reflectors: P = H_{i0} H_{i0+1} ... H_{i0+7}
//   = I - V T V^T,  T upper-tri (LAPACK larft forward recurrence).
// Per group: pass1 = gram(V^T V) + y (V^T h) in ONE 52-value butterfly reduce;
// tiny replicated T solve; z = T y; pass2 = h -= V z (rows re-read, L1-hot).
// Wave-autonomous: no LDS, no barriers.

#define N_DIM 2048
#define NR 32                    // rows per lane = N_DIM / 64
#define VC 2                     // batch columns per wave
#define KG 8                     // reflectors per group
#define WPB 4                    // waves per block
#define THREADS (WPB * 64)
#define NGRAM ((KG * (KG + 1)) / 2)   // 36: S[j][l] (l<=j) at j*(j+1)/2+l
#define NRED  (NGRAM + KG * VC)       // 52

__device__ __forceinline__ void accum_group(const float (&u)[KG],
                                            const float (&hr)[VC],
                                            float (&red)[NRED]) {
#pragma unroll
  for (int j = 0; j < KG; ++j) {
#pragma unroll
    for (int l = 0; l <= j; ++l)
      red[(j * (j + 1)) / 2 + l] = fmaf(u[j], u[l], red[(j * (j + 1)) / 2 + l]);
#pragma unroll
    for (int c = 0; c < VC; ++c)
      red[NGRAM + j * VC + c] = fmaf(u[j], hr[c], red[NGRAM + j * VC + c]);
  }
}

__global__ __launch_bounds__(THREADS, 2)
void OrthogonalTransform_house_kernel(const float* __restrict__ x,
                                      const float* __restrict__ w,
                                      float* __restrict__ out) {
  const int lane = threadIdx.x & 63;
  const int wave = threadIdx.x >> 6;
  const int gw   = blockIdx.x * WPB + wave;
  const int col0 = gw * VC;

  // h[k][c] = x[col0+c][lane + 64k]
  float h[NR][VC];
#pragma unroll
  for (int k = 0; k < NR; ++k) {
    const int r = lane + 64 * k;
#pragma unroll
    for (int c = 0; c < VC; ++c)
      h[k][c] = x[(size_t)(col0 + c) * N_DIM + r];
  }

  for (int i0 = N_DIM - KG; i0 >= 0; i0 -= KG) {
    const int ks = i0 >> 6;                       // straddling 64-row block
    const float* wb = w + (size_t)i0 * N_DIM;     // row i0

    float red[NRED];
#pragma unroll
    for (int t = 0; t < NRED; ++t) red[t] = 0.f;

    // ---------- pass 1: gram + y ----------
#pragma unroll
    for (int k = 0; k < NR; ++k) {
      const int r = lane + 64 * k;
      if (k > ks) {                               // fully active, no masks
        float u[KG];
#pragma unroll
        for (int j = 0; j < KG; ++j) u[j] = wb[(size_t)j * N_DIM + r];
        accum_group(u, h[k], red);
      } else if (k == ks) {                       // straddle: triu masks
        float u[KG];
#pragma unroll
        for (int j = 0; j < KG; ++j) {
          float t = wb[(size_t)j * N_DIM + r];
          u[j] = (r >= i0 + j) ? t : 0.f;
        }
        if (i0 == N_DIM - KG && r == N_DIM - 1) u[KG - 1] = 1.0f;  // U[-1,-1]=1
        accum_group(u, h[k], red);
      }
    }

    // one butterfly for all 52 values (per-level 52-way ILP)
#pragma unroll
    for (int m = 1; m < 64; m <<= 1)
#pragma unroll
      for (int t = 0; t < NRED; ++t)
        red[t] += __shfl_xor(red[t], m, 64);

    // ---------- T (upper-tri, larft forward) ----------
    float beta[KG];
#pragma unroll
    for (int j = 0; j < KG; ++j) {
      const float n2 = red[(j * (j + 1)) / 2 + j];
      beta[j] = (n2 > 0.f) ? 2.0f / n2 : 0.f;
    }
    float T[KG][KG];
#pragma unroll
    for (int j = 0; j < KG; ++j) {
      T[j][j] = beta[j];
#pragma unroll
      for (int r0 = 0; r0 < j; ++r0) {
        float acc = 0.f;
#pragma unroll
        for (int l = r0; l < j; ++l)
          acc = fmaf(T[r0][l], red[(j * (j + 1)) / 2 + l], acc);  // S(l,j), l<j
        T[r0][j] = -beta[j] * acc;
      }
    }

    // z = T * y   (y = red[NGRAM + j*VC + c])
    float z[KG][VC];
#pragma unroll
    for (int j = 0; j < KG; ++j)
#pragma unroll
      for (int c = 0; c < VC; ++c) {
        float acc = 0.f;
#pragma unroll
        for (int l = j; l < KG; ++l)
          acc = fmaf(T[j][l], red[NGRAM + l * VC + c], acc);
        z[j][c] = acc;
      }

    // ---------- pass 2: h -= V z ----------
#pragma unroll
    for (int k = 0; k < NR; ++k) {
      const int r = lane + 64 * k;
      if (k > ks) {
        float u[KG];
#pragma unroll
        for (int j = 0; j < KG; ++j) u[j] = wb[(size_t)j * N_DIM + r];
#pragma unroll
        for (int c = 0; c < VC; ++c) {
          float acc = h[k][c];
#pragma unroll
          for (int j = 0; j < KG; ++j) acc = fmaf(-u[j], z[j][c], acc);
          h[k][c] = acc;
        }
      } else if (k == ks) {
        float u[KG];
#pragma unroll
        for (int j = 0; j < KG; ++j) {
          float t = wb[(size_t)j * N_DIM + r];
          u[j] = (r >= i0 + j) ? t : 0.f;
        }
        if (i0 == N_DIM - KG && r == N_DIM - 1) u[KG - 1] = 1.0f;
#pragma unroll
        for (int c = 0; c < VC; ++c) {
          float acc = h[k][c];
#pragma unroll
          for (int j = 0; j < KG; ++j) acc = fmaf(-u[j], z[j][c], acc);
          h[k][c] = acc;
        }
      }
    }
  }

  // out[b][r] = h
#pragma unroll
  for (int k = 0; k < NR; ++k) {
    const int r = lane + 64 * k;
#pragma unroll
    for (int c = 0; c < VC; ++c)
      out[(size_t)(col0 + c) * N_DIM + r] = h[k][c];
  }
}

extern "C" void kernel_launch(void* const* d_in, const int* in_sizes, int n_in,
                              void* d_out, int out_size, void* d_ws, size_t ws_size,
                              hipStream_t stream) {
  const float* x = (const float*)d_in[0];   // (B, N) f32
  const float* w = (const float*)d_in[1];   // (N, M) f32
  float* out = (float*)d_out;               // (B, N) f32

  const int B = in_sizes[0] / N_DIM;            // 4096
  const int grid = B / (VC * WPB);              // 512 blocks -> 2048 waves

  OrthogonalTransform_house_kernel<<<grid, THREADS, 0, stream>>>(x, w, out);
}

// Round 3
// 2454.628 us; speedup vs baseline: 4.2894x; 2.3001x over previous
//
#include <hip/hip_runtime.h>

// OrthogonalTransform via hierarchical compact-WY aggregation.
//
// Reference: h <- H_i h for i = n-1 .. 0 (row i of U = triu(weight),
// U[n-1][n-1] = 1), i.e. out = X Q^T with Q = H_0 H_1 ... H_{n-1}.
//
// WY form: Q = I - W V^T, V[:,j] = u_j (= row j of masked U), built by
// log-depth pairwise merges:
//   (I - W_a V_a^T)(I - W_b V_b^T) = I - [W_a, W_b - W_a (V_a^T W_b)] [V_a,V_b]^T
// Base K=1: W[:,j] = beta_j u_j  (beta_j = 2/||u_j||^2 or 0).
// Storage is transposed (row-major rows = columns of V/W):
//   UM[j][c] = masked U,  WT[j][c] = W[c][j].
// Merge level k (pairs a=[a0,a0+k), b=[b0,b0+k), b0=a0+k):
//   Ct[q][p] = sum_c WT[b0+q][c] * UM[a0+p][c]          (NT-GEMM)
//   WT[b0+q][c] -= sum_p Ct[q][p] * WT[a0+p][c]         (NN-GEMM, in place)
// Apply: A1[i][j] = sum_{c>=j} X[i][c] UM[j][c]         (NT-GEMM, tri-skip)
//        out[i][c] = X[i][c] - sum_j A1[i][j] WT[j][c]  (NN-GEMM)

#define N_DIM 2048
#define NT64 (N_DIM / 64)          // 32 column tiles

// ---------------- ws layout (floats) ----------------
// beta : [0, 4096)
// UM   : [4096, 4096+4M)
// WT   : next 4M
// Ct   : next 1M   (level k uses (1024/k)*k^2 = 1024k <= 1M)
// A1   : next B*2048

// =================== small prep kernels ===================

__global__ __launch_bounds__(256)
void beta_kernel(const float* __restrict__ w, float* __restrict__ beta) {
  const int lane = threadIdx.x & 63;
  const int wv = threadIdx.x >> 6;
  const int j = blockIdx.x * 4 + wv;
  if (j >= N_DIM) return;
  float n2 = 0.f;
  for (int c = lane; c < N_DIM; c += 64) {
    float v = w[(size_t)j * N_DIM + c];
    if (j == N_DIM - 1 && c == N_DIM - 1) v = 1.0f;   // U[-1,-1] override
    if (c >= j) n2 = fmaf(v, v, n2);
  }
#pragma unroll
  for (int m = 1; m < 64; m <<= 1) n2 += __shfl_xor(n2, m, 64);
  if (lane == 0) beta[j] = (n2 > 0.f) ? 2.0f / n2 : 0.f;
}

__global__ __launch_bounds__(256)
void prep_kernel(const float* __restrict__ w, const float* __restrict__ beta,
                 float* __restrict__ UM, float* __restrict__ WT) {
  const size_t i4 = ((size_t)blockIdx.x * 256 + threadIdx.x) * 4;
  const int j = (int)(i4 >> 11);            // row
  const int c = (int)(i4 & (N_DIM - 1));    // col base
  const float bj = beta[j];
  const float* src = w + i4;
  float um[4], wt[4];
#pragma unroll
  for (int t = 0; t < 4; ++t) {
    float v = src[t];
    const int cc = c + t;
    if (j == N_DIM - 1 && cc == N_DIM - 1) v = 1.0f;
    v = (cc >= j) ? v : 0.f;
    um[t] = v;
    wt[t] = bj * v;
  }
  *(float4*)(UM + i4) = make_float4(um[0], um[1], um[2], um[3]);
  *(float4*)(WT + i4) = make_float4(wt[0], wt[1], wt[2], wt[3]);
}

// =================== tiled GEMM cores ===================
// 64x64 tile, 256 threads, 4x4 micro-tile, K-chunk 16 staged in LDS.

// D[mb+r][nb+q] = sum_{c>=c0} A[mb+r][c] * B[nb+q][c]   (both row-major, ld N_DIM)
__device__ __forceinline__
void nt_core(const float* __restrict__ A, int Ma,
             const float* __restrict__ B, int Nb,
             float* __restrict__ C, int ldc,
             int mb, int nb, int c0) {
  __shared__ float As[16][68];
  __shared__ float Bs[16][68];
  const int tid = threadIdx.x;
  const int tn = tid & 15, tm = tid >> 4;
  const int rowl = tid >> 2;          // 0..63
  const int kq = (tid & 3) << 2;      // 0,4,8,12
  float acc[4][4] = {};

  for (int c = c0; c < N_DIM; c += 16) {
    {
      const int r = mb + rowl;
      float4 v = make_float4(0.f, 0.f, 0.f, 0.f);
      if (r < Ma) v = *(const float4*)(A + (size_t)r * N_DIM + c + kq);
      As[kq + 0][rowl] = v.x; As[kq + 1][rowl] = v.y;
      As[kq + 2][rowl] = v.z; As[kq + 3][rowl] = v.w;
      const int r2 = nb + rowl;
      float4 u = make_float4(0.f, 0.f, 0.f, 0.f);
      if (r2 < Nb) u = *(const float4*)(B + (size_t)r2 * N_DIM + c + kq);
      Bs[kq + 0][rowl] = u.x; Bs[kq + 1][rowl] = u.y;
      Bs[kq + 2][rowl] = u.z; Bs[kq + 3][rowl] = u.w;
    }
    __syncthreads();
#pragma unroll
    for (int kk = 0; kk < 16; ++kk) {
      const float4 a4 = *(const float4*)&As[kk][tm * 4];
      const float4 b4 = *(const float4*)&Bs[kk][tn * 4];
      acc[0][0] = fmaf(a4.x, b4.x, acc[0][0]);
      acc[0][1] = fmaf(a4.x, b4.y, acc[0][1]);
      acc[0][2] = fmaf(a4.x, b4.z, acc[0][2]);
      acc[0][3] = fmaf(a4.x, b4.w, acc[0][3]);
      acc[1][0] = fmaf(a4.y, b4.x, acc[1][0]);
      acc[1][1] = fmaf(a4.y, b4.y, acc[1][1]);
      acc[1][2] = fmaf(a4.y, b4.z, acc[1][2]);
      acc[1][3] = fmaf(a4.y, b4.w, acc[1][3]);
      acc[2][0] = fmaf(a4.z, b4.x, acc[2][0]);
      acc[2][1] = fmaf(a4.z, b4.y, acc[2][1]);
      acc[2][2] = fmaf(a4.z, b4.z, acc[2][2]);
      acc[2][3] = fmaf(a4.z, b4.w, acc[2][3]);
      acc[3][0] = fmaf(a4.w, b4.x, acc[3][0]);
      acc[3][1] = fmaf(a4.w, b4.y, acc[3][1]);
      acc[3][2] = fmaf(a4.w, b4.z, acc[3][2]);
      acc[3][3] = fmaf(a4.w, b4.w, acc[3][3]);
    }
    __syncthreads();
  }

#pragma unroll
  for (int i = 0; i < 4; ++i) {
    const int r = mb + tm * 4 + i;
    if (r < Ma) {
#pragma unroll
      for (int jj = 0; jj < 4; ++jj) {
        const int q = nb + tn * 4 + jj;
        if (q < Nb) C[(size_t)r * ldc + q] = acc[i][jj];
      }
    }
  }
}

// out[rb+r][cb+c] = C0[rb+r][cb+c] - sum_{J<Ka} A[rb+r][J] * B[J][cb+c]
// A row-major (Ma x Ka, ld=lda); B row-major (Ka x N_DIM); C0/out ld N_DIM.
__device__ __forceinline__
void nn_core(const float* __restrict__ A, int Ma, int Ka, int lda,
             const float* __restrict__ B,
             const float* __restrict__ C0, float* __restrict__ out,
             int rb, int cb) {
  __shared__ float As[16][68];
  __shared__ float Bs[16][64];
  const int tid = threadIdx.x;
  const int tn = tid & 15, tm = tid >> 4;
  const int rowl = tid >> 2;
  const int kq = (tid & 3) << 2;
  const int kkb = tid >> 4;           // 0..15
  const int cc4 = (tid & 15) << 2;
  float acc[4][4] = {};

  for (int J = 0; J < Ka; J += 16) {
    {
      const int r = rb + rowl;
#pragma unroll
      for (int t = 0; t < 4; ++t) {
        const int Jc = J + kq + t;
        As[kq + t][rowl] = (r < Ma && Jc < Ka) ? A[(size_t)r * lda + Jc] : 0.f;
      }
      const int Jr = J + kkb;
      float4 v = make_float4(0.f, 0.f, 0.f, 0.f);
      if (Jr < Ka) v = *(const float4*)(B + (size_t)Jr * N_DIM + cb + cc4);
      *(float4*)&Bs[kkb][cc4] = v;
    }
    __syncthreads();
#pragma unroll
    for (int kk = 0; kk < 16; ++kk) {
      const float4 a4 = *(const float4*)&As[kk][tm * 4];
      const float4 b4 = *(const float4*)&Bs[kk][tn * 4];
      acc[0][0] = fmaf(a4.x, b4.x, acc[0][0]);
      acc[0][1] = fmaf(a4.x, b4.y, acc[0][1]);
      acc[0][2] = fmaf(a4.x, b4.z, acc[0][2]);
      acc[0][3] = fmaf(a4.x, b4.w, acc[0][3]);
      acc[1][0] = fmaf(a4.y, b4.x, acc[1][0]);
      acc[1][1] = fmaf(a4.y, b4.y, acc[1][1]);
      acc[1][2] = fmaf(a4.y, b4.z, acc[1][2]);
      acc[1][3] = fmaf(a4.y, b4.w, acc[1][3]);
      acc[2][0] = fmaf(a4.z, b4.x, acc[2][0]);
      acc[2][1] = fmaf(a4.z, b4.y, acc[2][1]);
      acc[2][2] = fmaf(a4.z, b4.z, acc[2][2]);
      acc[2][3] = fmaf(a4.z, b4.w, acc[2][3]);
      acc[3][0] = fmaf(a4.w, b4.x, acc[3][0]);
      acc[3][1] = fmaf(a4.w, b4.y, acc[3][1]);
      acc[3][2] = fmaf(a4.w, b4.z, acc[3][2]);
      acc[3][3] = fmaf(a4.w, b4.w, acc[3][3]);
    }
    __syncthreads();
  }

#pragma unroll
  for (int i = 0; i < 4; ++i) {
    const int r = rb + tm * 4 + i;
    if (r < Ma) {
#pragma unroll
      for (int jj = 0; jj < 4; ++jj) {
        const int c = cb + tn * 4 + jj;
        out[(size_t)r * N_DIM + c] = C0[(size_t)r * N_DIM + c] - acc[i][jj];
      }
    }
  }
}

// =================== wrappers ===================

__global__ __launch_bounds__(256)
void merge_ct_kernel(const float* __restrict__ WT, const float* __restrict__ UM,
                     float* __restrict__ Ct, int k) {
  const int tpm = (k + 63) >> 6;
  const int tiles = tpm * tpm;
  const int m = blockIdx.x / tiles;
  const int t = blockIdx.x % tiles;
  const int mb = (t / tpm) * 64;   // q tile (WT_b rows)
  const int nb = (t % tpm) * 64;   // p tile (UM_a rows)
  const int a0 = 2 * k * m, b0 = a0 + k;
  nt_core(WT + (size_t)b0 * N_DIM, k, UM + (size_t)a0 * N_DIM, k,
          Ct + (size_t)m * k * k, k, mb, nb, b0 & ~15);
}

__global__ __launch_bounds__(256)
void merge_update_kernel(float* __restrict__ WT, const float* __restrict__ Ct,
                         int k) {
  const int tpr = (k + 63) >> 6;
  const int tiles = tpr * NT64;
  const int m = blockIdx.x / tiles;
  const int t = blockIdx.x % tiles;
  const int rb = (t / NT64) * 64;
  const int cb = (t % NT64) * 64;
  const int a0 = 2 * k * m, b0 = a0 + k;
  if (cb + 64 <= a0) return;         // WT_a zero there -> no change
  nn_core(Ct + (size_t)m * k * k, k, k, k,
          WT + (size_t)a0 * N_DIM,
          WT + (size_t)b0 * N_DIM, WT + (size_t)b0 * N_DIM, rb, cb);
}

__global__ __launch_bounds__(256)
void gemm1_kernel(const float* __restrict__ X, const float* __restrict__ UM,
                  float* __restrict__ A1, int Bsz) {
  const int mb = (blockIdx.x / NT64) * 64;
  const int nb = (blockIdx.x % NT64) * 64;
  nt_core(X, Bsz, UM, N_DIM, A1, N_DIM, mb, nb, nb);   // tri-skip: c >= j-tile
}

__global__ __launch_bounds__(256)
void gemm2_kernel(const float* __restrict__ A1, const float* __restrict__ WT,
                  const float* __restrict__ X, float* __restrict__ out, int Bsz) {
  const int rb = (blockIdx.x / NT64) * 64;
  const int cb = (blockIdx.x % NT64) * 64;
  nn_core(A1, Bsz, N_DIM, N_DIM, WT, X, out, rb, cb);
}

// =================== fallback sweep (round-2 kernel) ===================

#define NRF 32
#define VCF 2
#define KGF 8
#define WPBF 4
#define NGRAMF ((KGF * (KGF + 1)) / 2)
#define NREDF (NGRAMF + KGF * VCF)

__device__ __forceinline__ void accum_group_f(const float (&u)[KGF],
                                              const float (&hr)[VCF],
                                              float (&red)[NREDF]) {
#pragma unroll
  for (int j = 0; j < KGF; ++j) {
#pragma unroll
    for (int l = 0; l <= j; ++l)
      red[(j * (j + 1)) / 2 + l] = fmaf(u[j], u[l], red[(j * (j + 1)) / 2 + l]);
#pragma unroll
    for (int c = 0; c < VCF; ++c)
      red[NGRAMF + j * VCF + c] = fmaf(u[j], hr[c], red[NGRAMF + j * VCF + c]);
  }
}

__global__ __launch_bounds__(256, 2)
void fallback_sweep_kernel(const float* __restrict__ x,
                           const float* __restrict__ w,
                           float* __restrict__ out) {
  const int lane = threadIdx.x & 63;
  const int wave = threadIdx.x >> 6;
  const int gw = blockIdx.x * WPBF + wave;
  const int col0 = gw * VCF;
  float h[NRF][VCF];
#pragma unroll
  for (int k = 0; k < NRF; ++k) {
    const int r = lane + 64 * k;
#pragma unroll
    for (int c = 0; c < VCF; ++c) h[k][c] = x[(size_t)(col0 + c) * N_DIM + r];
  }
  for (int i0 = N_DIM - KGF; i0 >= 0; i0 -= KGF) {
    const int ks = i0 >> 6;
    const float* wb = w + (size_t)i0 * N_DIM;
    float red[NREDF];
#pragma unroll
    for (int t = 0; t < NREDF; ++t) red[t] = 0.f;
#pragma unroll
    for (int k = 0; k < NRF; ++k) {
      const int r = lane + 64 * k;
      if (k > ks) {
        float u[KGF];
#pragma unroll
        for (int j = 0; j < KGF; ++j) u[j] = wb[(size_t)j * N_DIM + r];
        accum_group_f(u, h[k], red);
      } else if (k == ks) {
        float u[KGF];
#pragma unroll
        for (int j = 0; j < KGF; ++j) {
          float t = wb[(size_t)j * N_DIM + r];
          u[j] = (r >= i0 + j) ? t : 0.f;
        }
        if (i0 == N_DIM - KGF && r == N_DIM - 1) u[KGF - 1] = 1.0f;
        accum_group_f(u, h[k], red);
      }
    }
#pragma unroll
    for (int m = 1; m < 64; m <<= 1)
#pragma unroll
      for (int t = 0; t < NREDF; ++t) red[t] += __shfl_xor(red[t], m, 64);
    float beta[KGF];
#pragma unroll
    for (int j = 0; j < KGF; ++j) {
      const float n2 = red[(j * (j + 1)) / 2 + j];
      beta[j] = (n2 > 0.f) ? 2.0f / n2 : 0.f;
    }
    float T[KGF][KGF];
#pragma unroll
    for (int j = 0; j < KGF; ++j) {
      T[j][j] = beta[j];
#pragma unroll
      for (int r0 = 0; r0 < j; ++r0) {
        float acc = 0.f;
#pragma unroll
        for (int l = r0; l < j; ++l)
          acc = fmaf(T[r0][l], red[(j * (j + 1)) / 2 + l], acc);
        T[r0][j] = -beta[j] * acc;
      }
    }
    float z[KGF][VCF];
#pragma unroll
    for (int j = 0; j < KGF; ++j)
#pragma unroll
      for (int c = 0; c < VCF; ++c) {
        float acc = 0.f;
#pragma unroll
        for (int l = j; l < KGF; ++l)
          acc = fmaf(T[j][l], red[NGRAMF + l * VCF + c], acc);
        z[j][c] = acc;
      }
#pragma unroll
    for (int k = 0; k < NRF; ++k) {
      const int r = lane + 64 * k;
      if (k >= ks) {
        float u[KGF];
#pragma unroll
        for (int j = 0; j < KGF; ++j) {
          float t = wb[(size_t)j * N_DIM + r];
          u[j] = (k > ks || r >= i0 + j) ? t : 0.f;
        }
        if (i0 == N_DIM - KGF && r == N_DIM - 1) u[KGF - 1] = 1.0f;
#pragma unroll
        for (int c = 0; c < VCF; ++c) {
          float acc = h[k][c];
#pragma unroll
          for (int j = 0; j < KGF; ++j) acc = fmaf(-u[j], z[j][c], acc);
          h[k][c] = acc;
        }
      }
    }
  }
#pragma unroll
  for (int k = 0; k < NRF; ++k) {
    const int r = lane + 64 * k;
#pragma unroll
    for (int c = 0; c < VCF; ++c)
      out[(size_t)(col0 + c) * N_DIM + r] = h[k][c];
  }
}

// =================== launch ===================

extern "C" void kernel_launch(void* const* d_in, const int* in_sizes, int n_in,
                              void* d_out, int out_size, void* d_ws, size_t ws_size,
                              hipStream_t stream) {
  const float* x = (const float*)d_in[0];   // (B, N) f32
  const float* w = (const float*)d_in[1];   // (N, N) f32
  float* out = (float*)d_out;
  const int Bsz = in_sizes[0] / N_DIM;      // 4096

  const size_t NW = (size_t)N_DIM * N_DIM;  // 4M
  float* beta = (float*)d_ws;
  float* UM = beta + 4096;
  float* WT = UM + NW;
  float* Ct = WT + NW;
  float* A1 = Ct + (NW / 4);
  const size_t need =
      (4096 + 2 * NW + NW / 4 + (size_t)Bsz * N_DIM) * sizeof(float);

  if (ws_size < need) {
    fallback_sweep_kernel<<<Bsz / (VCF * WPBF), 256, 0, stream>>>(x, w, out);
    return;
  }

  beta_kernel<<<N_DIM / 4, 256, 0, stream>>>(w, beta);
  prep_kernel<<<(int)(NW / (4 * 256)), 256, 0, stream>>>(w, beta, UM, WT);

  for (int k = 1; k <= N_DIM / 2; k <<= 1) {
    const int mm = N_DIM / (2 * k);
    const int tpm = (k + 63) >> 6;
    merge_ct_kernel<<<mm * tpm * tpm, 256, 0, stream>>>(WT, UM, Ct, k);
    merge_update_kernel<<<mm * tpm * NT64, 256, 0, stream>>>(WT, Ct, k);
  }

  gemm1_kernel<<<(Bsz / 64) * NT64, 256, 0, stream>>>(x, UM, A1, Bsz);
  gemm2_kernel<<<(Bsz / 64) * NT64, 256, 0, stream>>>(A1, WT, x, out, Bsz);
}

// Round 4
// 1232.535 us; speedup vs baseline: 8.5424x; 1.9915x over previous
//
#include <hip/hip_runtime.h>

// OrthogonalTransform via hierarchical compact-WY + MFMA application.
//
// out = X Q^T, Q = H_0 H_1 ... H_{n-1}, H_i from row i of U = triu(weight),
// U[n-1][n-1] = 1.  Q = I - W V^T.
// Pipeline:
//   prep      : UM[j][c] = masked triu row (with U[-1,-1]=1 override)
//   base32    : per 32-group, gram + larft T recurrence -> WT rows = T^T UM
//   merges    : levels k = 32..1024 (fp32 cores, verified in round 3)
//   transpose : WTT[n][k] = WT[k][n]   (makes gemm2 an NT-GEMM)
//   gemm1     : A1 = X UM^T    (MFMA bf16 split-3, tri-skip k0 = nb)
//   gemm2     : out = X - A1 WTT^T  (MFMA bf16 split-3)

#define N_DIM 2048
#define NT64 32
#define NT128 16

typedef __attribute__((ext_vector_type(8))) short bf16x8;
typedef __attribute__((ext_vector_type(4))) float f32x4;

__device__ __forceinline__ unsigned short f2bf_rtne(float f) {
  unsigned u = __builtin_bit_cast(unsigned, f);
  u += 0x7FFFu + ((u >> 16) & 1u);
  return (unsigned short)(u >> 16);
}
__device__ __forceinline__ float bf2f(unsigned short h) {
  return __builtin_bit_cast(float, (unsigned)h << 16);
}

// =================== prep: UM only ===================

__global__ __launch_bounds__(256)
void prep_kernel(const float* __restrict__ w, float* __restrict__ UM) {
  const size_t i4 = ((size_t)blockIdx.x * 256 + threadIdx.x) * 4;
  const int j = (int)(i4 >> 11);
  const int c = (int)(i4 & (N_DIM - 1));
  const float4 v = *(const float4*)(w + i4);
  float f[4] = {v.x, v.y, v.z, v.w};
#pragma unroll
  for (int q = 0; q < 4; ++q) {
    const int cc = c + q;
    float val = f[q];
    if (j == N_DIM - 1 && cc == N_DIM - 1) val = 1.0f;
    f[q] = (cc >= j) ? val : 0.f;
  }
  *(float4*)(UM + i4) = make_float4(f[0], f[1], f[2], f[3]);
}

// =================== base32: direct 32-group WY ===================

__global__ __launch_bounds__(256)
void base32_kernel(const float* __restrict__ UM, float* __restrict__ WT) {
  __shared__ float Vs[32 * 132];
  __shared__ float Sg[32 * 33];
  __shared__ float Ts[32 * 33];
  const int t = threadIdx.x;
  const int i0 = blockIdx.x * 32;

  const int a2 = (t >> 4) * 2, b2 = (t & 15) * 2;
  float s00 = 0.f, s01 = 0.f, s10 = 0.f, s11 = 0.f;
  const int r0 = t >> 3;          // 0..31 (stage row)
  const int sg = (t & 7) * 16;    // stage col base

  // ---- gram S = V V^T (rows pre-masked; skip all-zero chunks) ----
  for (int cb = i0 & ~127; cb < N_DIM; cb += 128) {
    __syncthreads();
#pragma unroll
    for (int q = 0; q < 4; ++q) {
      const float4 v = *(const float4*)(UM + (size_t)(i0 + r0) * N_DIM + cb + sg + q * 4);
      *(float4*)&Vs[r0 * 132 + sg + q * 4] = v;
    }
    __syncthreads();
#pragma unroll 8
    for (int c = 0; c < 128; c += 4) {
      const float4 va0 = *(const float4*)&Vs[a2 * 132 + c];
      const float4 va1 = *(const float4*)&Vs[(a2 + 1) * 132 + c];
      const float4 vb0 = *(const float4*)&Vs[b2 * 132 + c];
      const float4 vb1 = *(const float4*)&Vs[(b2 + 1) * 132 + c];
      s00 = fmaf(va0.x, vb0.x, s00); s00 = fmaf(va0.y, vb0.y, s00);
      s00 = fmaf(va0.z, vb0.z, s00); s00 = fmaf(va0.w, vb0.w, s00);
      s01 = fmaf(va0.x, vb1.x, s01); s01 = fmaf(va0.y, vb1.y, s01);
      s01 = fmaf(va0.z, vb1.z, s01); s01 = fmaf(va0.w, vb1.w, s01);
      s10 = fmaf(va1.x, vb0.x, s10); s10 = fmaf(va1.y, vb0.y, s10);
      s10 = fmaf(va1.z, vb0.z, s10); s10 = fmaf(va1.w, vb0.w, s10);
      s11 = fmaf(va1.x, vb1.x, s11); s11 = fmaf(va1.y, vb1.y, s11);
      s11 = fmaf(va1.z, vb1.z, s11); s11 = fmaf(va1.w, vb1.w, s11);
    }
  }
  Sg[a2 * 33 + b2] = s00;
  Sg[a2 * 33 + b2 + 1] = s01;
  Sg[(a2 + 1) * 33 + b2] = s10;
  Sg[(a2 + 1) * 33 + b2 + 1] = s11;
  __syncthreads();

  // ---- T recurrence (larft forward): lane r owns row r ----
  for (int j = 0; j < 32; ++j) {
    if (t < 32) {
      const float sjj = Sg[j * 33 + j];
      const float bj = (sjj > 0.f) ? 2.0f / sjj : 0.f;
      float val;
      if (t == j) val = bj;
      else if (t > j) val = 0.f;
      else {
        float acc = 0.f;
        for (int ll = t; ll < j; ++ll)
          acc = fmaf(Ts[t * 33 + ll], Sg[ll * 33 + j], acc);
        val = -bj * acc;
      }
      Ts[t * 33 + j] = val;
    }
    __syncthreads();
  }

  // ---- WT rows: WT[i0+j][c] = sum_{l<=j} T[l][j] * UM[i0+l][c] ----
  const int jh = t >> 6;           // 0..3 -> rows jh*8..+7
  const int cc = (t & 63) * 2;
  for (int cb = 0; cb < N_DIM; cb += 128) {
    if (cb + 128 <= i0) {          // all-zero region (must still write: poison)
#pragma unroll
      for (int jj = 0; jj < 8; ++jj) {
        const int j = jh * 8 + jj;
        *(float2*)(WT + (size_t)(i0 + j) * N_DIM + cb + cc) = make_float2(0.f, 0.f);
      }
      continue;
    }
    __syncthreads();
#pragma unroll
    for (int q = 0; q < 4; ++q) {
      const float4 v = *(const float4*)(UM + (size_t)(i0 + r0) * N_DIM + cb + sg + q * 4);
      *(float4*)&Vs[r0 * 132 + sg + q * 4] = v;
    }
    __syncthreads();
#pragma unroll
    for (int jj = 0; jj < 8; ++jj) {
      const int j = jh * 8 + jj;
      float acc0 = 0.f, acc1 = 0.f;
      for (int ll = 0; ll <= j; ++ll) {
        const float tv = Ts[ll * 33 + j];
        acc0 = fmaf(tv, Vs[ll * 132 + cc], acc0);
        acc1 = fmaf(tv, Vs[ll * 132 + cc + 1], acc1);
      }
      *(float2*)(WT + (size_t)(i0 + j) * N_DIM + cb + cc) = make_float2(acc0, acc1);
    }
  }
}

// =================== fp32 tiled GEMM cores (round-3, verified) ===================

__device__ __forceinline__
void nt_core(const float* __restrict__ A, int Ma,
             const float* __restrict__ B, int Nb,
             float* __restrict__ C, int ldc,
             int mb, int nb, int c0) {
  __shared__ float As[16][68];
  __shared__ float Bs[16][68];
  const int tid = threadIdx.x;
  const int tn = tid & 15, tm = tid >> 4;
  const int rowl = tid >> 2;
  const int kq = (tid & 3) << 2;
  float acc[4][4] = {};

  for (int c = c0; c < N_DIM; c += 16) {
    {
      const int r = mb + rowl;
      float4 v = make_float4(0.f, 0.f, 0.f, 0.f);
      if (r < Ma) v = *(const float4*)(A + (size_t)r * N_DIM + c + kq);
      As[kq + 0][rowl] = v.x; As[kq + 1][rowl] = v.y;
      As[kq + 2][rowl] = v.z; As[kq + 3][rowl] = v.w;
      const int r2 = nb + rowl;
      float4 u = make_float4(0.f, 0.f, 0.f, 0.f);
      if (r2 < Nb) u = *(const float4*)(B + (size_t)r2 * N_DIM + c + kq);
      Bs[kq + 0][rowl] = u.x; Bs[kq + 1][rowl] = u.y;
      Bs[kq + 2][rowl] = u.z; Bs[kq + 3][rowl] = u.w;
    }
    __syncthreads();
#pragma unroll
    for (int kk = 0; kk < 16; ++kk) {
      const float4 a4 = *(const float4*)&As[kk][tm * 4];
      const float4 b4 = *(const float4*)&Bs[kk][tn * 4];
      acc[0][0] = fmaf(a4.x, b4.x, acc[0][0]);
      acc[0][1] = fmaf(a4.x, b4.y, acc[0][1]);
      acc[0][2] = fmaf(a4.x, b4.z, acc[0][2]);
      acc[0][3] = fmaf(a4.x, b4.w, acc[0][3]);
      acc[1][0] = fmaf(a4.y, b4.x, acc[1][0]);
      acc[1][1] = fmaf(a4.y, b4.y, acc[1][1]);
      acc[1][2] = fmaf(a4.y, b4.z, acc[1][2]);
      acc[1][3] = fmaf(a4.y, b4.w, acc[1][3]);
      acc[2][0] = fmaf(a4.z, b4.x, acc[2][0]);
      acc[2][1] = fmaf(a4.z, b4.y, acc[2][1]);
      acc[2][2] = fmaf(a4.z, b4.z, acc[2][2]);
      acc[2][3] = fmaf(a4.z, b4.w, acc[2][3]);
      acc[3][0] = fmaf(a4.w, b4.x, acc[3][0]);
      acc[3][1] = fmaf(a4.w, b4.y, acc[3][1]);
      acc[3][2] = fmaf(a4.w, b4.z, acc[3][2]);
      acc[3][3] = fmaf(a4.w, b4.w, acc[3][3]);
    }
    __syncthreads();
  }

#pragma unroll
  for (int i = 0; i < 4; ++i) {
    const int r = mb + tm * 4 + i;
    if (r < Ma) {
#pragma unroll
      for (int jj = 0; jj < 4; ++jj) {
        const int q = nb + tn * 4 + jj;
        if (q < Nb) C[(size_t)r * ldc + q] = acc[i][jj];
      }
    }
  }
}

__device__ __forceinline__
void nn_core(const float* __restrict__ A, int Ma, int Ka, int lda,
             const float* __restrict__ B,
             const float* __restrict__ C0, float* __restrict__ out,
             int rb, int cb) {
  __shared__ float As[16][68];
  __shared__ float Bs[16][64];
  const int tid = threadIdx.x;
  const int tn = tid & 15, tm = tid >> 4;
  const int rowl = tid >> 2;
  const int kq = (tid & 3) << 2;
  const int kkb = tid >> 4;
  const int cc4 = (tid & 15) << 2;
  float acc[4][4] = {};

  for (int J = 0; J < Ka; J += 16) {
    {
      const int r = rb + rowl;
#pragma unroll
      for (int t = 0; t < 4; ++t) {
        const int Jc = J + kq + t;
        As[kq + t][rowl] = (r < Ma && Jc < Ka) ? A[(size_t)r * lda + Jc] : 0.f;
      }
      const int Jr = J + kkb;
      float4 v = make_float4(0.f, 0.f, 0.f, 0.f);
      if (Jr < Ka) v = *(const float4*)(B + (size_t)Jr * N_DIM + cb + cc4);
      *(float4*)&Bs[kkb][cc4] = v;
    }
    __syncthreads();
#pragma unroll
    for (int kk = 0; kk < 16; ++kk) {
      const float4 a4 = *(const float4*)&As[kk][tm * 4];
      const float4 b4 = *(const float4*)&Bs[kk][tn * 4];
      acc[0][0] = fmaf(a4.x, b4.x, acc[0][0]);
      acc[0][1] = fmaf(a4.x, b4.y, acc[0][1]);
      acc[0][2] = fmaf(a4.x, b4.z, acc[0][2]);
      acc[0][3] = fmaf(a4.x, b4.w, acc[0][3]);
      acc[1][0] = fmaf(a4.y, b4.x, acc[1][0]);
      acc[1][1] = fmaf(a4.y, b4.y, acc[1][1]);
      acc[1][2] = fmaf(a4.y, b4.z, acc[1][2]);
      acc[1][3] = fmaf(a4.y, b4.w, acc[1][3]);
      acc[2][0] = fmaf(a4.z, b4.x, acc[2][0]);
      acc[2][1] = fmaf(a4.z, b4.y, acc[2][1]);
      acc[2][2] = fmaf(a4.z, b4.z, acc[2][2]);
      acc[2][3] = fmaf(a4.z, b4.w, acc[2][3]);
      acc[3][0] = fmaf(a4.w, b4.x, acc[3][0]);
      acc[3][1] = fmaf(a4.w, b4.y, acc[3][1]);
      acc[3][2] = fmaf(a4.w, b4.z, acc[3][2]);
      acc[3][3] = fmaf(a4.w, b4.w, acc[3][3]);
    }
    __syncthreads();
  }

#pragma unroll
  for (int i = 0; i < 4; ++i) {
    const int r = rb + tm * 4 + i;
    if (r < Ma) {
#pragma unroll
      for (int jj = 0; jj < 4; ++jj) {
        const int c = cb + tn * 4 + jj;
        out[(size_t)r * N_DIM + c] = C0[(size_t)r * N_DIM + c] - acc[i][jj];
      }
    }
  }
}

__global__ __launch_bounds__(256)
void merge_ct_kernel(const float* __restrict__ WT, const float* __restrict__ UM,
                     float* __restrict__ Ct, int k) {
  const int tpm = (k + 63) >> 6;
  const int tiles = tpm * tpm;
  const int m = blockIdx.x / tiles;
  const int t = blockIdx.x % tiles;
  const int mb = (t / tpm) * 64;
  const int nb = (t % tpm) * 64;
  const int a0 = 2 * k * m, b0 = a0 + k;
  nt_core(WT + (size_t)b0 * N_DIM, k, UM + (size_t)a0 * N_DIM, k,
          Ct + (size_t)m * k * k, k, mb, nb, b0 & ~15);
}

__global__ __launch_bounds__(256)
void merge_update_kernel(float* __restrict__ WT, const float* __restrict__ Ct,
                         int k) {
  const int tpr = (k + 63) >> 6;
  const int tiles = tpr * NT64;
  const int m = blockIdx.x / tiles;
  const int t = blockIdx.x % tiles;
  const int rb = (t / NT64) * 64;
  const int cb = (t % NT64) * 64;
  const int a0 = 2 * k * m, b0 = a0 + k;
  if (cb + 64 <= a0) return;
  nn_core(Ct + (size_t)m * k * k, k, k, k,
          WT + (size_t)a0 * N_DIM,
          WT + (size_t)b0 * N_DIM, WT + (size_t)b0 * N_DIM, rb, cb);
}

// =================== transpose WT -> WTT ===================

__global__ __launch_bounds__(256)
void transpose_kernel(const float* __restrict__ WT, float* __restrict__ WTT) {
  __shared__ float Tt[64 * 65];
  const int t = threadIdx.x;
  const int bk = (blockIdx.x & 31) * 64;
  const int bn = (blockIdx.x >> 5) * 64;
  const int r = t >> 2;
  const int s = (t & 3) * 16;
#pragma unroll
  for (int q = 0; q < 4; ++q) {
    const float4 v = *(const float4*)(WT + (size_t)(bk + r) * N_DIM + bn + s + q * 4);
    Tt[r * 65 + s + q * 4 + 0] = v.x;
    Tt[r * 65 + s + q * 4 + 1] = v.y;
    Tt[r * 65 + s + q * 4 + 2] = v.z;
    Tt[r * 65 + s + q * 4 + 3] = v.w;
  }
  __syncthreads();
#pragma unroll
  for (int q = 0; q < 4; ++q) {
    float4 o;
    o.x = Tt[(s + q * 4 + 0) * 65 + r];
    o.y = Tt[(s + q * 4 + 1) * 65 + r];
    o.z = Tt[(s + q * 4 + 2) * 65 + r];
    o.w = Tt[(s + q * 4 + 3) * 65 + r];
    *(float4*)(WTT + (size_t)(bn + r) * N_DIM + bk + s + q * 4) = o;
  }
}

// =================== MFMA NT-GEMM, bf16 hi/lo split-3 ===================
// C[m][n] = sum_k A[m][k] * Bm[n][k]  (both row-major, ld = N_DIM)
// EP==0: C = acc (fp32).  EP==1: C = X - acc.

__device__ __forceinline__ void stage_tile(const float* __restrict__ src,
                                           int rb, int kb, int t,
                                           unsigned short* __restrict__ Hd,
                                           unsigned short* __restrict__ Ld) {
  const int r0 = t >> 3;
  const int seg = (t & 7) * 4;
#pragma unroll
  for (int p = 0; p < 4; ++p) {
    const int row = r0 + p * 32;
    const float4 v = *(const float4*)(src + (size_t)(rb + row) * N_DIM + kb + seg);
    const float f[4] = {v.x, v.y, v.z, v.w};
    unsigned short h[4], l[4];
#pragma unroll
    for (int q = 0; q < 4; ++q) {
      h[q] = f2bf_rtne(f[q]);
      l[q] = f2bf_rtne(f[q] - bf2f(h[q]));
    }
    const int o = row * 40 + seg;
    *(uint2*)(Hd + o) = make_uint2((unsigned)h[0] | ((unsigned)h[1] << 16),
                                   (unsigned)h[2] | ((unsigned)h[3] << 16));
    *(uint2*)(Ld + o) = make_uint2((unsigned)l[0] | ((unsigned)l[1] << 16),
                                   (unsigned)l[2] | ((unsigned)l[3] << 16));
  }
}

template <int EP>
__global__ __launch_bounds__(256)
void gemm_mfma_kernel(const float* __restrict__ A, const float* __restrict__ Bm,
                      const float* __restrict__ X, float* __restrict__ C,
                      int tri) {
  __shared__ unsigned short Ah[128 * 40], Al[128 * 40], Bh[128 * 40], Bl[128 * 40];
  const int t = threadIdx.x;
  const int l = t & 63, w = t >> 6;
  const int wm = w >> 1, wn = w & 1;
  const int lrow = l & 15, lk = l >> 4;

  int bid = blockIdx.x;
  const int nwg = gridDim.x;
  if ((nwg & 7) == 0) {                 // XCD-chunked swizzle (bijective)
    const int q = nwg >> 3;
    bid = (bid & 7) * q + (bid >> 3);
  }
  const int mb = (bid / NT128) * 128;
  const int nb = (bid % NT128) * 128;
  const int k0 = tri ? nb : 0;

  f32x4 acc[4][4];
#pragma unroll
  for (int i = 0; i < 4; ++i)
#pragma unroll
    for (int j = 0; j < 4; ++j) {
      acc[i][j][0] = 0.f; acc[i][j][1] = 0.f;
      acc[i][j][2] = 0.f; acc[i][j][3] = 0.f;
    }

  for (int kb = k0; kb < N_DIM; kb += 32) {
    __syncthreads();
    stage_tile(A, mb, kb, t, Ah, Al);
    stage_tile(Bm, nb, kb, t, Bh, Bl);
    __syncthreads();

    bf16x8 ah[4], al[4], bh[4], bl[4];
#pragma unroll
    for (int fm = 0; fm < 4; ++fm) {
      const int o = (wm * 64 + fm * 16 + lrow) * 40 + lk * 8;
      ah[fm] = *(const bf16x8*)(Ah + o);
      al[fm] = *(const bf16x8*)(Al + o);
    }
#pragma unroll
    for (int fn = 0; fn < 4; ++fn) {
      const int o = (wn * 64 + fn * 16 + lrow) * 40 + lk * 8;
      bh[fn] = *(const bf16x8*)(Bh + o);
      bl[fn] = *(const bf16x8*)(Bl + o);
    }
#pragma unroll
    for (int fm = 0; fm < 4; ++fm)
#pragma unroll
      for (int fn = 0; fn < 4; ++fn) {
        acc[fm][fn] = __builtin_amdgcn_mfma_f32_16x16x32_bf16(ah[fm], bh[fn], acc[fm][fn], 0, 0, 0);
        acc[fm][fn] = __builtin_amdgcn_mfma_f32_16x16x32_bf16(ah[fm], bl[fn], acc[fm][fn], 0, 0, 0);
        acc[fm][fn] = __builtin_amdgcn_mfma_f32_16x16x32_bf16(al[fm], bh[fn], acc[fm][fn], 0, 0, 0);
      }
  }

#pragma unroll
  for (int fm = 0; fm < 4; ++fm) {
    const int m0 = mb + wm * 64 + fm * 16 + lk * 4;
#pragma unroll
    for (int fn = 0; fn < 4; ++fn) {
      const int n = nb + wn * 64 + fn * 16 + lrow;
#pragma unroll
      for (int r = 0; r < 4; ++r) {
        const size_t idx = (size_t)(m0 + r) * N_DIM + n;
        if (EP == 0) C[idx] = acc[fm][fn][r];
        else C[idx] = X[idx] - acc[fm][fn][r];
      }
    }
  }
}

// =================== fallback sweep (round-2, verified) ===================

#define NRF 32
#define VCF 2
#define KGF 8
#define WPBF 4
#define NGRAMF ((KGF * (KGF + 1)) / 2)
#define NREDF (NGRAMF + KGF * VCF)

__device__ __forceinline__ void accum_group_f(const float (&u)[KGF],
                                              const float (&hr)[VCF],
                                              float (&red)[NREDF]) {
#pragma unroll
  for (int j = 0; j < KGF; ++j) {
#pragma unroll
    for (int l = 0; l <= j; ++l)
      red[(j * (j + 1)) / 2 + l] = fmaf(u[j], u[l], red[(j * (j + 1)) / 2 + l]);
#pragma unroll
    for (int c = 0; c < VCF; ++c)
      red[NGRAMF + j * VCF + c] = fmaf(u[j], hr[c], red[NGRAMF + j * VCF + c]);
  }
}

__global__ __launch_bounds__(256, 2)
void fallback_sweep_kernel(const float* __restrict__ x,
                           const float* __restrict__ w,
                           float* __restrict__ out) {
  const int lane = threadIdx.x & 63;
  const int wave = threadIdx.x >> 6;
  const int gw = blockIdx.x * WPBF + wave;
  const int col0 = gw * VCF;
  float h[NRF][VCF];
#pragma unroll
  for (int k = 0; k < NRF; ++k) {
    const int r = lane + 64 * k;
#pragma unroll
    for (int c = 0; c < VCF; ++c) h[k][c] = x[(size_t)(col0 + c) * N_DIM + r];
  }
  for (int i0 = N_DIM - KGF; i0 >= 0; i0 -= KGF) {
    const int ks = i0 >> 6;
    const float* wb = w + (size_t)i0 * N_DIM;
    float red[NREDF];
#pragma unroll
    for (int t = 0; t < NREDF; ++t) red[t] = 0.f;
#pragma unroll
    for (int k = 0; k < NRF; ++k) {
      const int r = lane + 64 * k;
      if (k > ks) {
        float u[KGF];
#pragma unroll
        for (int j = 0; j < KGF; ++j) u[j] = wb[(size_t)j * N_DIM + r];
        accum_group_f(u, h[k], red);
      } else if (k == ks) {
        float u[KGF];
#pragma unroll
        for (int j = 0; j < KGF; ++j) {
          float tt = wb[(size_t)j * N_DIM + r];
          u[j] = (r >= i0 + j) ? tt : 0.f;
        }
        if (i0 == N_DIM - KGF && r == N_DIM - 1) u[KGF - 1] = 1.0f;
        accum_group_f(u, h[k], red);
      }
    }
#pragma unroll
    for (int m = 1; m < 64; m <<= 1)
#pragma unroll
      for (int t = 0; t < NREDF; ++t) red[t] += __shfl_xor(red[t], m, 64);
    float beta[KGF];
#pragma unroll
    for (int j = 0; j < KGF; ++j) {
      const float n2 = red[(j * (j + 1)) / 2 + j];
      beta[j] = (n2 > 0.f) ? 2.0f / n2 : 0.f;
    }
    float T[KGF][KGF];
#pragma unroll
    for (int j = 0; j < KGF; ++j) {
      T[j][j] = beta[j];
#pragma unroll
      for (int r0 = 0; r0 < j; ++r0) {
        float acc = 0.f;
#pragma unroll
        for (int l = r0; l < j; ++l)
          acc = fmaf(T[r0][l], red[(j * (j + 1)) / 2 + l], acc);
        T[r0][j] = -beta[j] * acc;
      }
    }
    float z[KGF][VCF];
#pragma unroll
    for (int j = 0; j < KGF; ++j)
#pragma unroll
      for (int c = 0; c < VCF; ++c) {
        float acc = 0.f;
#pragma unroll
        for (int l = j; l < KGF; ++l)
          acc = fmaf(T[j][l], red[NGRAMF + l * VCF + c], acc);
        z[j][c] = acc;
      }
#pragma unroll
    for (int k = 0; k < NRF; ++k) {
      const int r = lane + 64 * k;
      if (k >= ks) {
        float u[KGF];
#pragma unroll
        for (int j = 0; j < KGF; ++j) {
          float tt = wb[(size_t)j * N_DIM + r];
          u[j] = (k > ks || r >= i0 + j) ? tt : 0.f;
        }
        if (i0 == N_DIM - KGF && r == N_DIM - 1) u[KGF - 1] = 1.0f;
#pragma unroll
        for (int c = 0; c < VCF; ++c) {
          float acc = h[k][c];
#pragma unroll
          for (int j = 0; j < KGF; ++j) acc = fmaf(-u[j], z[j][c], acc);
          h[k][c] = acc;
        }
      }
    }
  }
#pragma unroll
  for (int k = 0; k < NRF; ++k) {
    const int r = lane + 64 * k;
#pragma unroll
    for (int c = 0; c < VCF; ++c)
      out[(size_t)(col0 + c) * N_DIM + r] = h[k][c];
  }
}

// =================== launch ===================

extern "C" void kernel_launch(void* const* d_in, const int* in_sizes, int n_in,
                              void* d_out, int out_size, void* d_ws, size_t ws_size,
                              hipStream_t stream) {
  const float* x = (const float*)d_in[0];   // (B, N) f32
  const float* w = (const float*)d_in[1];   // (N, N) f32
  float* out = (float*)d_out;
  const int Bsz = in_sizes[0] / N_DIM;      // 4096

  const size_t NW = (size_t)N_DIM * N_DIM;  // 4M floats
  float* UM  = (float*)d_ws;
  float* WTT = UM + NW;
  float* WT  = WTT + NW;
  float* Ct  = WT + NW;
  float* A1  = WT;                          // aliases [WT, WT + Bsz*N): WT+Ct dead by gemm1

  const size_t tail = ((size_t)Bsz * N_DIM > NW + NW / 4) ? (size_t)Bsz * N_DIM
                                                          : NW + NW / 4;
  const size_t need = (2 * NW + tail) * sizeof(float);

  if (ws_size < need || (Bsz % 128) != 0) {
    fallback_sweep_kernel<<<Bsz / (VCF * WPBF), 256, 0, stream>>>(x, w, out);
    return;
  }

  prep_kernel<<<(int)(NW / 1024), 256, 0, stream>>>(w, UM);
  base32_kernel<<<64, 256, 0, stream>>>(UM, WT);

  for (int k = 32; k <= N_DIM / 2; k <<= 1) {
    const int mm = N_DIM / (2 * k);
    const int tpm = (k + 63) >> 6;
    merge_ct_kernel<<<mm * tpm * tpm, 256, 0, stream>>>(WT, UM, Ct, k);
    merge_update_kernel<<<mm * tpm * NT64, 256, 0, stream>>>(WT, Ct, k);
  }

  transpose_kernel<<<1024, 256, 0, stream>>>(WT, WTT);

  const int grid = (Bsz / 128) * NT128;     // 512
  gemm_mfma_kernel<0><<<grid, 256, 0, stream>>>(x, UM, nullptr, A1, 1);
  gemm_mfma_kernel<1><<<grid, 256, 0, stream>>>(A1, WTT, x, out, 0);
}

// Round 5
// 804.643 us; speedup vs baseline: 13.0851x; 1.5318x over previous
//
#include <hip/hip_runtime.h>

// OrthogonalTransform via hierarchical compact-WY + MFMA application.
// out = X Q^T, Q = H_0...H_{n-1}, U = triu(weight), U[-1,-1] = 1.
// Pipeline:
//   prep      : UM = masked triu rows (fp32)
//   base32    : per-32 group gram + larft T -> WT rows (fp32)   [proven r4]
//   merges    : k = 32..1024, split-K ct (partials+reduce) + update (fp32)
//   trans_conv: WT -> WTTh/WTTl (transpose + bf16 hi/lo split)
//   um_conv   : UM -> UMh/UMl
//   gemm1     : A1h/l = bf16split(X UM^T)  (MFMA split-3, tri-skip, X conv on fly)
//   gemm2     : out = X - A1 WTT^T         (MFMA split-3, all operands pre-split)
//
// ws layout (floats, 16M total = 64 MB, same "need" as round 4):
//   [0,4M)   WT   -> later A1h (8M shorts)
//   [4M,8M)  UM   -> later A1l
//   [8M,12M) WTTh + WTTl (4M+4M shorts)
//   [12M,16M) Ct(1M) + Pt(1M) -> later UMh + UMl (4M+4M shorts)

#define N_DIM 2048
#define NT64 32
#define NT128 16

typedef __attribute__((ext_vector_type(8))) short bf16x8;
typedef __attribute__((ext_vector_type(4))) float f32x4;
typedef unsigned short ushort_t;

__device__ __forceinline__ ushort_t f2bf_rtne(float f) {
  unsigned u = __builtin_bit_cast(unsigned, f);
  u += 0x7FFFu + ((u >> 16) & 1u);
  return (ushort_t)(u >> 16);
}
__device__ __forceinline__ float bf2f(ushort_t h) {
  return __builtin_bit_cast(float, (unsigned)h << 16);
}

// =================== prep ===================

__global__ __launch_bounds__(256)
void prep_kernel(const float* __restrict__ w, float* __restrict__ UM) {
  const size_t i4 = ((size_t)blockIdx.x * 256 + threadIdx.x) * 4;
  const int j = (int)(i4 >> 11);
  const int c = (int)(i4 & (N_DIM - 1));
  const float4 v = *(const float4*)(w + i4);
  float f[4] = {v.x, v.y, v.z, v.w};
#pragma unroll
  for (int q = 0; q < 4; ++q) {
    const int cc = c + q;
    float val = f[q];
    if (j == N_DIM - 1 && cc == N_DIM - 1) val = 1.0f;
    f[q] = (cc >= j) ? val : 0.f;
  }
  *(float4*)(UM + i4) = make_float4(f[0], f[1], f[2], f[3]);
}

// =================== base32 (unchanged, proven) ===================

__global__ __launch_bounds__(256)
void base32_kernel(const float* __restrict__ UM, float* __restrict__ WT) {
  __shared__ float Vs[32 * 132];
  __shared__ float Sg[32 * 33];
  __shared__ float Ts[32 * 33];
  const int t = threadIdx.x;
  const int i0 = blockIdx.x * 32;

  const int a2 = (t >> 4) * 2, b2 = (t & 15) * 2;
  float s00 = 0.f, s01 = 0.f, s10 = 0.f, s11 = 0.f;
  const int r0 = t >> 3;
  const int sg = (t & 7) * 16;

  for (int cb = i0 & ~127; cb < N_DIM; cb += 128) {
    __syncthreads();
#pragma unroll
    for (int q = 0; q < 4; ++q) {
      const float4 v = *(const float4*)(UM + (size_t)(i0 + r0) * N_DIM + cb + sg + q * 4);
      *(float4*)&Vs[r0 * 132 + sg + q * 4] = v;
    }
    __syncthreads();
#pragma unroll 8
    for (int c = 0; c < 128; c += 4) {
      const float4 va0 = *(const float4*)&Vs[a2 * 132 + c];
      const float4 va1 = *(const float4*)&Vs[(a2 + 1) * 132 + c];
      const float4 vb0 = *(const float4*)&Vs[b2 * 132 + c];
      const float4 vb1 = *(const float4*)&Vs[(b2 + 1) * 132 + c];
      s00 = fmaf(va0.x, vb0.x, s00); s00 = fmaf(va0.y, vb0.y, s00);
      s00 = fmaf(va0.z, vb0.z, s00); s00 = fmaf(va0.w, vb0.w, s00);
      s01 = fmaf(va0.x, vb1.x, s01); s01 = fmaf(va0.y, vb1.y, s01);
      s01 = fmaf(va0.z, vb1.z, s01); s01 = fmaf(va0.w, vb1.w, s01);
      s10 = fmaf(va1.x, vb0.x, s10); s10 = fmaf(va1.y, vb0.y, s10);
      s10 = fmaf(va1.z, vb0.z, s10); s10 = fmaf(va1.w, vb0.w, s10);
      s11 = fmaf(va1.x, vb1.x, s11); s11 = fmaf(va1.y, vb1.y, s11);
      s11 = fmaf(va1.z, vb1.z, s11); s11 = fmaf(va1.w, vb1.w, s11);
    }
  }
  Sg[a2 * 33 + b2] = s00;
  Sg[a2 * 33 + b2 + 1] = s01;
  Sg[(a2 + 1) * 33 + b2] = s10;
  Sg[(a2 + 1) * 33 + b2 + 1] = s11;
  __syncthreads();

  for (int j = 0; j < 32; ++j) {
    if (t < 32) {
      const float sjj = Sg[j * 33 + j];
      const float bj = (sjj > 0.f) ? 2.0f / sjj : 0.f;
      float val;
      if (t == j) val = bj;
      else if (t > j) val = 0.f;
      else {
        float acc = 0.f;
        for (int ll = t; ll < j; ++ll)
          acc = fmaf(Ts[t * 33 + ll], Sg[ll * 33 + j], acc);
        val = -bj * acc;
      }
      Ts[t * 33 + j] = val;
    }
    __syncthreads();
  }

  const int jh = t >> 6;
  const int cc = (t & 63) * 2;
  for (int cb = 0; cb < N_DIM; cb += 128) {
    if (cb + 128 <= i0) {
#pragma unroll
      for (int jj = 0; jj < 8; ++jj) {
        const int j = jh * 8 + jj;
        *(float2*)(WT + (size_t)(i0 + j) * N_DIM + cb + cc) = make_float2(0.f, 0.f);
      }
      continue;
    }
    __syncthreads();
#pragma unroll
    for (int q = 0; q < 4; ++q) {
      const float4 v = *(const float4*)(UM + (size_t)(i0 + r0) * N_DIM + cb + sg + q * 4);
      *(float4*)&Vs[r0 * 132 + sg + q * 4] = v;
    }
    __syncthreads();
#pragma unroll
    for (int jj = 0; jj < 8; ++jj) {
      const int j = jh * 8 + jj;
      float acc0 = 0.f, acc1 = 0.f;
      for (int ll = 0; ll <= j; ++ll) {
        const float tv = Ts[ll * 33 + j];
        acc0 = fmaf(tv, Vs[ll * 132 + cc], acc0);
        acc1 = fmaf(tv, Vs[ll * 132 + cc + 1], acc1);
      }
      *(float2*)(WT + (size_t)(i0 + j) * N_DIM + cb + cc) = make_float2(acc0, acc1);
    }
  }
}

// =================== fp32 GEMM cores ===================

__device__ __forceinline__
void nt_core(const float* __restrict__ A, int Ma,
             const float* __restrict__ B, int Nb,
             float* __restrict__ C, int ldc,
             int mb, int nb, int cbeg, int cend) {
  __shared__ float As[16][68];
  __shared__ float Bs[16][68];
  const int tid = threadIdx.x;
  const int tn = tid & 15, tm = tid >> 4;
  const int rowl = tid >> 2;
  const int kq = (tid & 3) << 2;
  float acc[4][4] = {};

  for (int c = cbeg; c < cend; c += 16) {
    {
      const int r = mb + rowl;
      float4 v = make_float4(0.f, 0.f, 0.f, 0.f);
      if (r < Ma) v = *(const float4*)(A + (size_t)r * N_DIM + c + kq);
      As[kq + 0][rowl] = v.x; As[kq + 1][rowl] = v.y;
      As[kq + 2][rowl] = v.z; As[kq + 3][rowl] = v.w;
      const int r2 = nb + rowl;
      float4 u = make_float4(0.f, 0.f, 0.f, 0.f);
      if (r2 < Nb) u = *(const float4*)(B + (size_t)r2 * N_DIM + c + kq);
      Bs[kq + 0][rowl] = u.x; Bs[kq + 1][rowl] = u.y;
      Bs[kq + 2][rowl] = u.z; Bs[kq + 3][rowl] = u.w;
    }
    __syncthreads();
#pragma unroll
    for (int kk = 0; kk < 16; ++kk) {
      const float4 a4 = *(const float4*)&As[kk][tm * 4];
      const float4 b4 = *(const float4*)&Bs[kk][tn * 4];
      acc[0][0] = fmaf(a4.x, b4.x, acc[0][0]);
      acc[0][1] = fmaf(a4.x, b4.y, acc[0][1]);
      acc[0][2] = fmaf(a4.x, b4.z, acc[0][2]);
      acc[0][3] = fmaf(a4.x, b4.w, acc[0][3]);
      acc[1][0] = fmaf(a4.y, b4.x, acc[1][0]);
      acc[1][1] = fmaf(a4.y, b4.y, acc[1][1]);
      acc[1][2] = fmaf(a4.y, b4.z, acc[1][2]);
      acc[1][3] = fmaf(a4.y, b4.w, acc[1][3]);
      acc[2][0] = fmaf(a4.z, b4.x, acc[2][0]);
      acc[2][1] = fmaf(a4.z, b4.y, acc[2][1]);
      acc[2][2] = fmaf(a4.z, b4.z, acc[2][2]);
      acc[2][3] = fmaf(a4.z, b4.w, acc[2][3]);
      acc[3][0] = fmaf(a4.w, b4.x, acc[3][0]);
      acc[3][1] = fmaf(a4.w, b4.y, acc[3][1]);
      acc[3][2] = fmaf(a4.w, b4.z, acc[3][2]);
      acc[3][3] = fmaf(a4.w, b4.w, acc[3][3]);
    }
    __syncthreads();
  }

#pragma unroll
  for (int i = 0; i < 4; ++i) {
    const int r = mb + tm * 4 + i;
    if (r < Ma) {
#pragma unroll
      for (int jj = 0; jj < 4; ++jj) {
        const int q = nb + tn * 4 + jj;
        if (q < Nb) C[(size_t)r * ldc + q] = acc[i][jj];
      }
    }
  }
}

__device__ __forceinline__
void nn_core(const float* __restrict__ A, int Ma, int Ka, int lda,
             const float* __restrict__ B,
             const float* __restrict__ C0, float* __restrict__ out,
             int rb, int cb) {
  __shared__ float As[16][68];
  __shared__ float Bs[16][64];
  const int tid = threadIdx.x;
  const int tn = tid & 15, tm = tid >> 4;
  const int rowl = tid >> 2;
  const int kq = (tid & 3) << 2;
  const int kkb = tid >> 4;
  const int cc4 = (tid & 15) << 2;
  float acc[4][4] = {};

  for (int J = 0; J < Ka; J += 16) {
    {
      const int r = rb + rowl;
#pragma unroll
      for (int t = 0; t < 4; ++t) {
        const int Jc = J + kq + t;
        As[kq + t][rowl] = (r < Ma && Jc < Ka) ? A[(size_t)r * lda + Jc] : 0.f;
      }
      const int Jr = J + kkb;
      float4 v = make_float4(0.f, 0.f, 0.f, 0.f);
      if (Jr < Ka) v = *(const float4*)(B + (size_t)Jr * N_DIM + cb + cc4);
      *(float4*)&Bs[kkb][cc4] = v;
    }
    __syncthreads();
#pragma unroll
    for (int kk = 0; kk < 16; ++kk) {
      const float4 a4 = *(const float4*)&As[kk][tm * 4];
      const float4 b4 = *(const float4*)&Bs[kk][tn * 4];
      acc[0][0] = fmaf(a4.x, b4.x, acc[0][0]);
      acc[0][1] = fmaf(a4.x, b4.y, acc[0][1]);
      acc[0][2] = fmaf(a4.x, b4.z, acc[0][2]);
      acc[0][3] = fmaf(a4.x, b4.w, acc[0][3]);
      acc[1][0] = fmaf(a4.y, b4.x, acc[1][0]);
      acc[1][1] = fmaf(a4.y, b4.y, acc[1][1]);
      acc[1][2] = fmaf(a4.y, b4.z, acc[1][2]);
      acc[1][3] = fmaf(a4.y, b4.w, acc[1][3]);
      acc[2][0] = fmaf(a4.z, b4.x, acc[2][0]);
      acc[2][1] = fmaf(a4.z, b4.y, acc[2][1]);
      acc[2][2] = fmaf(a4.z, b4.z, acc[2][2]);
      acc[2][3] = fmaf(a4.z, b4.w, acc[2][3]);
      acc[3][0] = fmaf(a4.w, b4.x, acc[3][0]);
      acc[3][1] = fmaf(a4.w, b4.y, acc[3][1]);
      acc[3][2] = fmaf(a4.w, b4.z, acc[3][2]);
      acc[3][3] = fmaf(a4.w, b4.w, acc[3][3]);
    }
    __syncthreads();
  }

#pragma unroll
  for (int i = 0; i < 4; ++i) {
    const int r = rb + tm * 4 + i;
    if (r < Ma) {
#pragma unroll
      for (int jj = 0; jj < 4; ++jj) {
        const int c = cb + tn * 4 + jj;
        out[(size_t)r * N_DIM + c] = C0[(size_t)r * N_DIM + c] - acc[i][jj];
      }
    }
  }
}

// =================== merge wrappers (split-K ct) ===================

__global__ __launch_bounds__(256)
void merge_ct_splitk(const float* __restrict__ WT, const float* __restrict__ UM,
                     float* __restrict__ Pt, int k, int SK) {
  const int tpm = (k + 63) >> 6;
  const int tiles = tpm * tpm;
  const int per_pair = tiles * SK;
  const int m = blockIdx.x / per_pair;
  const int rest = blockIdx.x % per_pair;
  const int sk = rest / tiles;
  const int t2 = rest % tiles;
  const int mb = (t2 / tpm) * 64;
  const int nb = (t2 % tpm) * 64;
  const int a0 = 2 * k * m, b0 = a0 + k;
  const int c0 = b0 & ~15;
  const int len = N_DIM - c0;
  const int step = ((len + SK - 1) / SK + 15) & ~15;
  int cbeg = c0 + sk * step;
  int cend = cbeg + step;
  if (cbeg > N_DIM) cbeg = N_DIM;
  if (cend > N_DIM) cend = N_DIM;
  const int mm = N_DIM / (2 * k);
  float* dst = Pt + (size_t)sk * mm * k * k + (size_t)m * k * k;
  nt_core(WT + (size_t)b0 * N_DIM, k, UM + (size_t)a0 * N_DIM, k,
          dst, k, mb, nb, cbeg, cend);
}

__global__ __launch_bounds__(256)
void ct_reduce(const float* __restrict__ Pt, float* __restrict__ Ct,
               int n, int SK) {
  const int i4 = (blockIdx.x * 256 + threadIdx.x) * 4;
  if (i4 >= n) return;
  float4 s = *(const float4*)(Pt + i4);
  for (int sk = 1; sk < SK; ++sk) {
    const float4 v = *(const float4*)(Pt + (size_t)sk * n + i4);
    s.x += v.x; s.y += v.y; s.z += v.z; s.w += v.w;
  }
  *(float4*)(Ct + i4) = s;
}

__global__ __launch_bounds__(256)
void merge_update_kernel(float* __restrict__ WT, const float* __restrict__ Ct,
                         int k) {
  const int tpr = (k + 63) >> 6;
  const int tiles = tpr * NT64;
  const int m = blockIdx.x / tiles;
  const int t = blockIdx.x % tiles;
  const int rb = (t / NT64) * 64;
  const int cb = (t % NT64) * 64;
  const int a0 = 2 * k * m, b0 = a0 + k;
  if (cb + 64 <= a0) return;
  nn_core(Ct + (size_t)m * k * k, k, k, k,
          WT + (size_t)a0 * N_DIM,
          WT + (size_t)b0 * N_DIM, WT + (size_t)b0 * N_DIM, rb, cb);
}

// =================== conversions ===================

__global__ __launch_bounds__(256)
void trans_conv_kernel(const float* __restrict__ WT,
                       ushort_t* __restrict__ WTTh, ushort_t* __restrict__ WTTl) {
  __shared__ float Tt[64 * 65];
  const int t = threadIdx.x;
  const int bk = (blockIdx.x & 31) * 64;
  const int bn = (blockIdx.x >> 5) * 64;
  const int r = t >> 2;
  const int s = (t & 3) * 16;
#pragma unroll
  for (int q = 0; q < 4; ++q) {
    const float4 v = *(const float4*)(WT + (size_t)(bk + r) * N_DIM + bn + s + q * 4);
    Tt[r * 65 + s + q * 4 + 0] = v.x;
    Tt[r * 65 + s + q * 4 + 1] = v.y;
    Tt[r * 65 + s + q * 4 + 2] = v.z;
    Tt[r * 65 + s + q * 4 + 3] = v.w;
  }
  __syncthreads();
#pragma unroll
  for (int q = 0; q < 4; ++q) {
    float f[4];
    f[0] = Tt[(s + q * 4 + 0) * 65 + r];
    f[1] = Tt[(s + q * 4 + 1) * 65 + r];
    f[2] = Tt[(s + q * 4 + 2) * 65 + r];
    f[3] = Tt[(s + q * 4 + 3) * 65 + r];
    ushort_t h[4], l[4];
#pragma unroll
    for (int e = 0; e < 4; ++e) {
      h[e] = f2bf_rtne(f[e]);
      l[e] = f2bf_rtne(f[e] - bf2f(h[e]));
    }
    const size_t o = (size_t)(bn + r) * N_DIM + bk + s + q * 4;
    *(uint2*)(WTTh + o) = make_uint2((unsigned)h[0] | ((unsigned)h[1] << 16),
                                     (unsigned)h[2] | ((unsigned)h[3] << 16));
    *(uint2*)(WTTl + o) = make_uint2((unsigned)l[0] | ((unsigned)l[1] << 16),
                                     (unsigned)l[2] | ((unsigned)l[3] << 16));
  }
}

__global__ __launch_bounds__(256)
void um_conv_kernel(const float* __restrict__ UM,
                    ushort_t* __restrict__ UMh, ushort_t* __restrict__ UMl) {
  const size_t i4 = ((size_t)blockIdx.x * 256 + threadIdx.x) * 4;
  const float4 v = *(const float4*)(UM + i4);
  const float f[4] = {v.x, v.y, v.z, v.w};
  ushort_t h[4], l[4];
#pragma unroll
  for (int e = 0; e < 4; ++e) {
    h[e] = f2bf_rtne(f[e]);
    l[e] = f2bf_rtne(f[e] - bf2f(h[e]));
  }
  *(uint2*)(UMh + i4) = make_uint2((unsigned)h[0] | ((unsigned)h[1] << 16),
                                   (unsigned)h[2] | ((unsigned)h[3] << 16));
  *(uint2*)(UMl + i4) = make_uint2((unsigned)l[0] | ((unsigned)l[1] << 16),
                                   (unsigned)l[2] | ((unsigned)l[3] << 16));
}

// =================== MFMA GEMM (split-3) ===================

__device__ __forceinline__ void stage_f32(const float* __restrict__ src,
                                          int rb, int kb, int t,
                                          ushort_t* __restrict__ Hd,
                                          ushort_t* __restrict__ Ld) {
  const int r0 = t >> 3;
  const int seg = (t & 7) * 4;
#pragma unroll
  for (int p = 0; p < 4; ++p) {
    const int row = r0 + p * 32;
    const float4 v = *(const float4*)(src + (size_t)(rb + row) * N_DIM + kb + seg);
    const float f[4] = {v.x, v.y, v.z, v.w};
    ushort_t h[4], l[4];
#pragma unroll
    for (int q = 0; q < 4; ++q) {
      h[q] = f2bf_rtne(f[q]);
      l[q] = f2bf_rtne(f[q] - bf2f(h[q]));
    }
    const int o = row * 40 + seg;
    *(uint2*)(Hd + o) = make_uint2((unsigned)h[0] | ((unsigned)h[1] << 16),
                                   (unsigned)h[2] | ((unsigned)h[3] << 16));
    *(uint2*)(Ld + o) = make_uint2((unsigned)l[0] | ((unsigned)l[1] << 16),
                                   (unsigned)l[2] | ((unsigned)l[3] << 16));
  }
}

__device__ __forceinline__ void stage_pre(const ushort_t* __restrict__ H,
                                          const ushort_t* __restrict__ L,
                                          int rb, int kb, int t,
                                          ushort_t* __restrict__ Hd,
                                          ushort_t* __restrict__ Ld) {
  const int r0 = t >> 1;                 // 0..127
  const int seg = (t & 1) << 4;          // 0 or 16 shorts
  const size_t g = (size_t)(rb + r0) * N_DIM + kb + seg;
  const int o = r0 * 40 + seg;
  *(bf16x8*)(Hd + o) = *(const bf16x8*)(H + g);
  *(bf16x8*)(Hd + o + 8) = *(const bf16x8*)(H + g + 8);
  *(bf16x8*)(Ld + o) = *(const bf16x8*)(L + g);
  *(bf16x8*)(Ld + o + 8) = *(const bf16x8*)(L + g + 8);
}

// ASRC: 1 = A fp32 (convert on fly), 0 = A pre-split bf16 pair.
// EP:   1 = Cf = X - acc ;  2 = write Ch/Cl = bf16split(acc).
template <int ASRC, int EP>
__global__ __launch_bounds__(256)
void gemm_bf_kernel(const float* __restrict__ Af,
                    const ushort_t* __restrict__ Ahg, const ushort_t* __restrict__ Alg,
                    const ushort_t* __restrict__ Bhg, const ushort_t* __restrict__ Blg,
                    const float* __restrict__ X, float* __restrict__ Cf,
                    ushort_t* __restrict__ Ch, ushort_t* __restrict__ Cl,
                    int tri) {
  __shared__ ushort_t Ahs[128 * 40], Als[128 * 40], Bhs[128 * 40], Bls[128 * 40];
  const int t = threadIdx.x;
  const int l = t & 63, w = t >> 6;
  const int wm = w >> 1, wn = w & 1;
  const int lrow = l & 15, lk = l >> 4;

  int bid = blockIdx.x;
  const int nwg = gridDim.x;
  if ((nwg & 7) == 0) {
    const int q = nwg >> 3;
    bid = (bid & 7) * q + (bid >> 3);
  }
  const int mb = (bid / NT128) * 128;
  const int nb = (bid % NT128) * 128;
  const int k0 = tri ? nb : 0;

  f32x4 acc[4][4];
#pragma unroll
  for (int i = 0; i < 4; ++i)
#pragma unroll
    for (int j = 0; j < 4; ++j) {
      acc[i][j][0] = 0.f; acc[i][j][1] = 0.f;
      acc[i][j][2] = 0.f; acc[i][j][3] = 0.f;
    }

  for (int kb = k0; kb < N_DIM; kb += 32) {
    __syncthreads();
    if (ASRC) stage_f32(Af, mb, kb, t, Ahs, Als);
    else      stage_pre(Ahg, Alg, mb, kb, t, Ahs, Als);
    stage_pre(Bhg, Blg, nb, kb, t, Bhs, Bls);
    __syncthreads();

    bf16x8 ah[4], al[4], bh[4], bl[4];
#pragma unroll
    for (int fm = 0; fm < 4; ++fm) {
      const int o = (wm * 64 + fm * 16 + lrow) * 40 + lk * 8;
      ah[fm] = *(const bf16x8*)(Ahs + o);
      al[fm] = *(const bf16x8*)(Als + o);
    }
#pragma unroll
    for (int fn = 0; fn < 4; ++fn) {
      const int o = (wn * 64 + fn * 16 + lrow) * 40 + lk * 8;
      bh[fn] = *(const bf16x8*)(Bhs + o);
      bl[fn] = *(const bf16x8*)(Bls + o);
    }
#pragma unroll
    for (int fm = 0; fm < 4; ++fm)
#pragma unroll
      for (int fn = 0; fn < 4; ++fn) {
        acc[fm][fn] = __builtin_amdgcn_mfma_f32_16x16x32_bf16(ah[fm], bh[fn], acc[fm][fn], 0, 0, 0);
        acc[fm][fn] = __builtin_amdgcn_mfma_f32_16x16x32_bf16(ah[fm], bl[fn], acc[fm][fn], 0, 0, 0);
        acc[fm][fn] = __builtin_amdgcn_mfma_f32_16x16x32_bf16(al[fm], bh[fn], acc[fm][fn], 0, 0, 0);
      }
  }

#pragma unroll
  for (int fm = 0; fm < 4; ++fm) {
    const int m0 = mb + wm * 64 + fm * 16 + lk * 4;
#pragma unroll
    for (int fn = 0; fn < 4; ++fn) {
      const int n = nb + wn * 64 + fn * 16 + lrow;
#pragma unroll
      for (int r = 0; r < 4; ++r) {
        const size_t idx = (size_t)(m0 + r) * N_DIM + n;
        const float f = acc[fm][fn][r];
        if (EP == 1) {
          Cf[idx] = X[idx] - f;
        } else {
          const ushort_t h = f2bf_rtne(f);
          Ch[idx] = h;
          Cl[idx] = f2bf_rtne(f - bf2f(h));
        }
      }
    }
  }
}

// =================== fallback sweep (round-2, proven) ===================

#define NRF 32
#define VCF 2
#define KGF 8
#define WPBF 4
#define NGRAMF ((KGF * (KGF + 1)) / 2)
#define NREDF (NGRAMF + KGF * VCF)

__device__ __forceinline__ void accum_group_f(const float (&u)[KGF],
                                              const float (&hr)[VCF],
                                              float (&red)[NREDF]) {
#pragma unroll
  for (int j = 0; j < KGF; ++j) {
#pragma unroll
    for (int l = 0; l <= j; ++l)
      red[(j * (j + 1)) / 2 + l] = fmaf(u[j], u[l], red[(j * (j + 1)) / 2 + l]);
#pragma unroll
    for (int c = 0; c < VCF; ++c)
      red[NGRAMF + j * VCF + c] = fmaf(u[j], hr[c], red[NGRAMF + j * VCF + c]);
  }
}

__global__ __launch_bounds__(256, 2)
void fallback_sweep_kernel(const float* __restrict__ x,
                           const float* __restrict__ w,
                           float* __restrict__ out) {
  const int lane = threadIdx.x & 63;
  const int wave = threadIdx.x >> 6;
  const int gw = blockIdx.x * WPBF + wave;
  const int col0 = gw * VCF;
  float h[NRF][VCF];
#pragma unroll
  for (int k = 0; k < NRF; ++k) {
    const int r = lane + 64 * k;
#pragma unroll
    for (int c = 0; c < VCF; ++c) h[k][c] = x[(size_t)(col0 + c) * N_DIM + r];
  }
  for (int i0 = N_DIM - KGF; i0 >= 0; i0 -= KGF) {
    const int ks = i0 >> 6;
    const float* wb = w + (size_t)i0 * N_DIM;
    float red[NREDF];
#pragma unroll
    for (int t = 0; t < NREDF; ++t) red[t] = 0.f;
#pragma unroll
    for (int k = 0; k < NRF; ++k) {
      const int r = lane + 64 * k;
      if (k > ks) {
        float u[KGF];
#pragma unroll
        for (int j = 0; j < KGF; ++j) u[j] = wb[(size_t)j * N_DIM + r];
        accum_group_f(u, h[k], red);
      } else if (k == ks) {
        float u[KGF];
#pragma unroll
        for (int j = 0; j < KGF; ++j) {
          float tt = wb[(size_t)j * N_DIM + r];
          u[j] = (r >= i0 + j) ? tt : 0.f;
        }
        if (i0 == N_DIM - KGF && r == N_DIM - 1) u[KGF - 1] = 1.0f;
        accum_group_f(u, h[k], red);
      }
    }
#pragma unroll
    for (int m = 1; m < 64; m <<= 1)
#pragma unroll
      for (int t = 0; t < NREDF; ++t) red[t] += __shfl_xor(red[t], m, 64);
    float beta[KGF];
#pragma unroll
    for (int j = 0; j < KGF; ++j) {
      const float n2 = red[(j * (j + 1)) / 2 + j];
      beta[j] = (n2 > 0.f) ? 2.0f / n2 : 0.f;
    }
    float T[KGF][KGF];
#pragma unroll
    for (int j = 0; j < KGF; ++j) {
      T[j][j] = beta[j];
#pragma unroll
      for (int r0 = 0; r0 < j; ++r0) {
        float acc = 0.f;
#pragma unroll
        for (int l = r0; l < j; ++l)
          acc = fmaf(T[r0][l], red[(j * (j + 1)) / 2 + l], acc);
        T[r0][j] = -beta[j] * acc;
      }
    }
    float z[KGF][VCF];
#pragma unroll
    for (int j = 0; j < KGF; ++j)
#pragma unroll
      for (int c = 0; c < VCF; ++c) {
        float acc = 0.f;
#pragma unroll
        for (int l = j; l < KGF; ++l)
          acc = fmaf(T[j][l], red[NGRAMF + l * VCF + c], acc);
        z[j][c] = acc;
      }
#pragma unroll
    for (int k = 0; k < NRF; ++k) {
      const int r = lane + 64 * k;
      if (k >= ks) {
        float u[KGF];
#pragma unroll
        for (int j = 0; j < KGF; ++j) {
          float tt = wb[(size_t)j * N_DIM + r];
          u[j] = (k > ks || r >= i0 + j) ? tt : 0.f;
        }
        if (i0 == N_DIM - KGF && r == N_DIM - 1) u[KGF - 1] = 1.0f;
#pragma unroll
        for (int c = 0; c < VCF; ++c) {
          float acc = h[k][c];
#pragma unroll
          for (int j = 0; j < KGF; ++j) acc = fmaf(-u[j], z[j][c], acc);
          h[k][c] = acc;
        }
      }
    }
  }
#pragma unroll
  for (int k = 0; k < NRF; ++k) {
    const int r = lane + 64 * k;
#pragma unroll
    for (int c = 0; c < VCF; ++c)
      out[(size_t)(col0 + c) * N_DIM + r] = h[k][c];
  }
}

// =================== launch ===================

extern "C" void kernel_launch(void* const* d_in, const int* in_sizes, int n_in,
                              void* d_out, int out_size, void* d_ws, size_t ws_size,
                              hipStream_t stream) {
  const float* x = (const float*)d_in[0];
  const float* w = (const float*)d_in[1];
  float* out = (float*)d_out;
  const int Bsz = in_sizes[0] / N_DIM;      // 4096

  const size_t NW = (size_t)N_DIM * N_DIM;  // 4M floats
  float* ws = (float*)d_ws;

  float* WT = ws;                           // [0, 4M)
  float* UM = ws + NW;                      // [4M, 8M)
  ushort_t* WTTh = (ushort_t*)(ws + 2 * NW);        // [8M,10M) floats
  ushort_t* WTTl = WTTh + NW;                       // [10M,12M)
  float* Ct = ws + 3 * NW;                  // [12M,13M)
  float* Pt = ws + 3 * NW + NW / 4;         // [13M,14M)
  ushort_t* UMh = (ushort_t*)(ws + 3 * NW);         // [12M,14M) (after merges)
  ushort_t* UMl = UMh + NW;                         // [14M,16M)
  ushort_t* A1h = (ushort_t*)ws;                    // [0,4M)  (after trans_conv)
  ushort_t* A1l = (ushort_t*)(ws + NW);             // [4M,8M) (after um_conv)

  const size_t need = 4 * NW * sizeof(float);       // 64 MB (same as round 4)

  if (ws_size < need || (Bsz % 128) != 0) {
    fallback_sweep_kernel<<<Bsz / (VCF * WPBF), 256, 0, stream>>>(x, w, out);
    return;
  }

  prep_kernel<<<(int)(NW / 1024), 256, 0, stream>>>(w, UM);
  base32_kernel<<<64, 256, 0, stream>>>(UM, WT);

  for (int k = 32; k <= N_DIM / 2; k <<= 1) {
    const int mm = N_DIM / (2 * k);
    const int tpm = (k + 63) >> 6;
    const int tiles = tpm * tpm;
    int SK = 256 / (mm * tiles);
    if (SK < 1) SK = 1;
    if (SK > 16) SK = 16;
    float* dst = (SK == 1) ? Ct : Pt;
    merge_ct_splitk<<<mm * tiles * SK, 256, 0, stream>>>(WT, UM, dst, k, SK);
    if (SK > 1) {
      const int n = mm * k * k;
      ct_reduce<<<(n + 1023) / 1024, 256, 0, stream>>>(Pt, Ct, n, SK);
    }
    merge_update_kernel<<<mm * tpm * NT64, 256, 0, stream>>>(WT, Ct, k);
  }

  trans_conv_kernel<<<1024, 256, 0, stream>>>(WT, WTTh, WTTl);
  um_conv_kernel<<<(int)(NW / 1024), 256, 0, stream>>>(UM, UMh, UMl);

  const int grid = (Bsz / 128) * NT128;     // 512
  // gemm1: A1h/l = split(X UM^T), tri-skip
  gemm_bf_kernel<1, 2><<<grid, 256, 0, stream>>>(
      x, nullptr, nullptr, UMh, UMl, nullptr, nullptr, A1h, A1l, 1);
  // gemm2: out = X - A1 WTT^T
  gemm_bf_kernel<0, 1><<<grid, 256, 0, stream>>>(
      nullptr, A1h, A1l, WTTh, WTTl, x, out, nullptr, nullptr, 0);
}

// Round 6
// 676.731 us; speedup vs baseline: 15.5584x; 1.1890x over previous
//
#include <hip/hip_runtime.h>

// OrthogonalTransform via hierarchical compact-WY + MFMA application.
// out = X Q^T, Q = H_0...H_{n-1}, U = triu(weight), U[-1,-1] = 1.
// Pipeline:
//   prep          : UM = masked triu rows (fp32)
//   gram32_partial: 64 groups x 8 col-chunks -> partial 32x32 grams (Pg)
//   t32           : reduce partials + larft recurrence -> Tg (64 x 32x32)
//   wt32          : WT rows = T^T UM per (group, 128-col tile)
//   merges k=32,64: fp32 split-K ct + reduce + update  [proven r5]
//   merges k>=128 : MFMA split-3 ct (split-K partials) + MFMA NN update
//   trans_conv    : WT -> WTTh/WTTl (transpose + bf16 hi/lo split)
//   um_conv       : UM -> UMh/UMl
//   gemm1         : A1h/l = bf16split(X UM^T)  (MFMA split-3, tri-skip)
//   gemm2         : out = X - A1 WTT^T         (MFMA split-3, pre-split)
//
// ws layout (floats, 16M = 64 MB):
//   [0,4M)    WT    -> later A1h/A1l (shorts)
//   [4M,8M)   UM
//   [8M,12M)  WTTh + WTTl (shorts)
//   [12M,13M) Ct   (also Pg during base phase)
//   [13M,14M) Pt   (also Tg during base phase)
//   [12M,16M) UMh + UMl (after merges)

#define N_DIM 2048
#define NT64 32
#define NT128 16

typedef __attribute__((ext_vector_type(8))) short bf16x8;
typedef __attribute__((ext_vector_type(4))) float f32x4;
typedef unsigned short ushort_t;

__device__ __forceinline__ ushort_t f2bf_rtne(float f) {
  unsigned u = __builtin_bit_cast(unsigned, f);
  u += 0x7FFFu + ((u >> 16) & 1u);
  return (ushort_t)(u >> 16);
}
__device__ __forceinline__ float bf2f(ushort_t h) {
  return __builtin_bit_cast(float, (unsigned)h << 16);
}

// =================== prep ===================

__global__ __launch_bounds__(256)
void prep_kernel(const float* __restrict__ w, float* __restrict__ UM) {
  const size_t i4 = ((size_t)blockIdx.x * 256 + threadIdx.x) * 4;
  const int j = (int)(i4 >> 11);
  const int c = (int)(i4 & (N_DIM - 1));
  const float4 v = *(const float4*)(w + i4);
  float f[4] = {v.x, v.y, v.z, v.w};
#pragma unroll
  for (int q = 0; q < 4; ++q) {
    const int cc = c + q;
    float val = f[q];
    if (j == N_DIM - 1 && cc == N_DIM - 1) val = 1.0f;
    f[q] = (cc >= j) ? val : 0.f;
  }
  *(float4*)(UM + i4) = make_float4(f[0], f[1], f[2], f[3]);
}

// =================== base32 replacement (parallel) ===================

__global__ __launch_bounds__(256)
void gram32_partial(const float* __restrict__ UM, float* __restrict__ Pg) {
  const int g = blockIdx.x >> 3;
  const int s = blockIdx.x & 7;
  const int i0 = g * 32;
  const int t = threadIdx.x;
  float* dst = Pg + (size_t)blockIdx.x * 1024;
  if ((s + 1) * 256 <= i0) {                 // all-zero column range
    *(float4*)(dst + t * 4) = make_float4(0.f, 0.f, 0.f, 0.f);
    return;
  }
  __shared__ float Vs[32 * 132];
  const int a2 = (t >> 4) * 2, b2 = (t & 15) * 2;
  const int r0 = t >> 3, sg = (t & 7) * 16;
  float s00 = 0.f, s01 = 0.f, s10 = 0.f, s11 = 0.f;
  for (int cb = s * 256; cb < s * 256 + 256; cb += 128) {
    __syncthreads();
#pragma unroll
    for (int q = 0; q < 4; ++q) {
      const float4 v = *(const float4*)(UM + (size_t)(i0 + r0) * N_DIM + cb + sg + q * 4);
      *(float4*)&Vs[r0 * 132 + sg + q * 4] = v;
    }
    __syncthreads();
#pragma unroll 8
    for (int c = 0; c < 128; c += 4) {
      const float4 va0 = *(const float4*)&Vs[a2 * 132 + c];
      const float4 va1 = *(const float4*)&Vs[(a2 + 1) * 132 + c];
      const float4 vb0 = *(const float4*)&Vs[b2 * 132 + c];
      const float4 vb1 = *(const float4*)&Vs[(b2 + 1) * 132 + c];
      s00 = fmaf(va0.x, vb0.x, s00); s00 = fmaf(va0.y, vb0.y, s00);
      s00 = fmaf(va0.z, vb0.z, s00); s00 = fmaf(va0.w, vb0.w, s00);
      s01 = fmaf(va0.x, vb1.x, s01); s01 = fmaf(va0.y, vb1.y, s01);
      s01 = fmaf(va0.z, vb1.z, s01); s01 = fmaf(va0.w, vb1.w, s01);
      s10 = fmaf(va1.x, vb0.x, s10); s10 = fmaf(va1.y, vb0.y, s10);
      s10 = fmaf(va1.z, vb0.z, s10); s10 = fmaf(va1.w, vb0.w, s10);
      s11 = fmaf(va1.x, vb1.x, s11); s11 = fmaf(va1.y, vb1.y, s11);
      s11 = fmaf(va1.z, vb1.z, s11); s11 = fmaf(va1.w, vb1.w, s11);
    }
  }
  dst[a2 * 32 + b2] = s00;
  dst[a2 * 32 + b2 + 1] = s01;
  dst[(a2 + 1) * 32 + b2] = s10;
  dst[(a2 + 1) * 32 + b2 + 1] = s11;
}

__global__ __launch_bounds__(256)
void t32_kernel(const float* __restrict__ Pg, float* __restrict__ Tg) {
  __shared__ float Sg[32 * 33];
  __shared__ float Ts[32 * 33];
  const int g = blockIdx.x;
  const int t = threadIdx.x;
#pragma unroll
  for (int q = 0; q < 4; ++q) {
    const int e = t * 4 + q;
    float ssum = 0.f;
    for (int s = 0; s < 8; ++s) ssum += Pg[(size_t)(g * 8 + s) * 1024 + e];
    Sg[(e >> 5) * 33 + (e & 31)] = ssum;
  }
  __syncthreads();
  for (int j = 0; j < 32; ++j) {
    if (t < 32) {
      const float sjj = Sg[j * 33 + j];
      const float bj = (sjj > 0.f) ? 2.0f / sjj : 0.f;
      float val;
      if (t == j) val = bj;
      else if (t > j) val = 0.f;
      else {
        float acc = 0.f;
        for (int ll = t; ll < j; ++ll)
          acc = fmaf(Ts[t * 33 + ll], Sg[ll * 33 + j], acc);
        val = -bj * acc;
      }
      Ts[t * 33 + j] = val;
    }
    __syncthreads();
  }
#pragma unroll
  for (int q = 0; q < 4; ++q) {
    const int e = t * 4 + q;
    Tg[(size_t)g * 1024 + e] = Ts[(e >> 5) * 33 + (e & 31)];
  }
}

__global__ __launch_bounds__(256)
void wt32_kernel(const float* __restrict__ UM, const float* __restrict__ Tg,
                 float* __restrict__ WT) {
  const int g = blockIdx.x >> 4;
  const int ctile = blockIdx.x & 15;
  const int i0 = g * 32;
  const int cb = ctile * 128;
  const int t = threadIdx.x;
  const int jh = t >> 6;
  const int cc = (t & 63) * 2;
  if (cb + 128 <= i0) {                      // zero region (poisoned ws!)
#pragma unroll
    for (int jj = 0; jj < 8; ++jj) {
      const int j = jh * 8 + jj;
      *(float2*)(WT + (size_t)(i0 + j) * N_DIM + cb + cc) = make_float2(0.f, 0.f);
    }
    return;
  }
  __shared__ float Vs[32 * 132];
  __shared__ float Ts[32 * 33];
#pragma unroll
  for (int q = 0; q < 4; ++q) {
    const int e = t * 4 + q;
    Ts[(e >> 5) * 33 + (e & 31)] = Tg[(size_t)g * 1024 + e];
  }
  const int r0 = t >> 3, sg = (t & 7) * 16;
#pragma unroll
  for (int q = 0; q < 4; ++q) {
    const float4 v = *(const float4*)(UM + (size_t)(i0 + r0) * N_DIM + cb + sg + q * 4);
    *(float4*)&Vs[r0 * 132 + sg + q * 4] = v;
  }
  __syncthreads();
#pragma unroll
  for (int jj = 0; jj < 8; ++jj) {
    const int j = jh * 8 + jj;
    float acc0 = 0.f, acc1 = 0.f;
    for (int ll = 0; ll <= j; ++ll) {
      const float tv = Ts[ll * 33 + j];
      acc0 = fmaf(tv, Vs[ll * 132 + cc], acc0);
      acc1 = fmaf(tv, Vs[ll * 132 + cc + 1], acc1);
    }
    *(float2*)(WT + (size_t)(i0 + j) * N_DIM + cb + cc) = make_float2(acc0, acc1);
  }
}

// =================== fp32 GEMM cores (small-k ladder, proven) ===================

__device__ __forceinline__
void nt_core(const float* __restrict__ A, int Ma,
             const float* __restrict__ B, int Nb,
             float* __restrict__ C, int ldc,
             int mb, int nb, int cbeg, int cend) {
  __shared__ float As[16][68];
  __shared__ float Bs[16][68];
  const int tid = threadIdx.x;
  const int tn = tid & 15, tm = tid >> 4;
  const int rowl = tid >> 2;
  const int kq = (tid & 3) << 2;
  float acc[4][4] = {};

  for (int c = cbeg; c < cend; c += 16) {
    {
      const int r = mb + rowl;
      float4 v = make_float4(0.f, 0.f, 0.f, 0.f);
      if (r < Ma) v = *(const float4*)(A + (size_t)r * N_DIM + c + kq);
      As[kq + 0][rowl] = v.x; As[kq + 1][rowl] = v.y;
      As[kq + 2][rowl] = v.z; As[kq + 3][rowl] = v.w;
      const int r2 = nb + rowl;
      float4 u = make_float4(0.f, 0.f, 0.f, 0.f);
      if (r2 < Nb) u = *(const float4*)(B + (size_t)r2 * N_DIM + c + kq);
      Bs[kq + 0][rowl] = u.x; Bs[kq + 1][rowl] = u.y;
      Bs[kq + 2][rowl] = u.z; Bs[kq + 3][rowl] = u.w;
    }
    __syncthreads();
#pragma unroll
    for (int kk = 0; kk < 16; ++kk) {
      const float4 a4 = *(const float4*)&As[kk][tm * 4];
      const float4 b4 = *(const float4*)&Bs[kk][tn * 4];
      acc[0][0] = fmaf(a4.x, b4.x, acc[0][0]);
      acc[0][1] = fmaf(a4.x, b4.y, acc[0][1]);
      acc[0][2] = fmaf(a4.x, b4.z, acc[0][2]);
      acc[0][3] = fmaf(a4.x, b4.w, acc[0][3]);
      acc[1][0] = fmaf(a4.y, b4.x, acc[1][0]);
      acc[1][1] = fmaf(a4.y, b4.y, acc[1][1]);
      acc[1][2] = fmaf(a4.y, b4.z, acc[1][2]);
      acc[1][3] = fmaf(a4.y, b4.w, acc[1][3]);
      acc[2][0] = fmaf(a4.z, b4.x, acc[2][0]);
      acc[2][1] = fmaf(a4.z, b4.y, acc[2][1]);
      acc[2][2] = fmaf(a4.z, b4.z, acc[2][2]);
      acc[2][3] = fmaf(a4.z, b4.w, acc[2][3]);
      acc[3][0] = fmaf(a4.w, b4.x, acc[3][0]);
      acc[3][1] = fmaf(a4.w, b4.y, acc[3][1]);
      acc[3][2] = fmaf(a4.w, b4.z, acc[3][2]);
      acc[3][3] = fmaf(a4.w, b4.w, acc[3][3]);
    }
    __syncthreads();
  }

#pragma unroll
  for (int i = 0; i < 4; ++i) {
    const int r = mb + tm * 4 + i;
    if (r < Ma) {
#pragma unroll
      for (int jj = 0; jj < 4; ++jj) {
        const int q = nb + tn * 4 + jj;
        if (q < Nb) C[(size_t)r * ldc + q] = acc[i][jj];
      }
    }
  }
}

__device__ __forceinline__
void nn_core(const float* __restrict__ A, int Ma, int Ka, int lda,
             const float* __restrict__ B,
             const float* __restrict__ C0, float* __restrict__ out,
             int rb, int cb) {
  __shared__ float As[16][68];
  __shared__ float Bs[16][64];
  const int tid = threadIdx.x;
  const int tn = tid & 15, tm = tid >> 4;
  const int rowl = tid >> 2;
  const int kq = (tid & 3) << 2;
  const int kkb = tid >> 4;
  const int cc4 = (tid & 15) << 2;
  float acc[4][4] = {};

  for (int J = 0; J < Ka; J += 16) {
    {
      const int r = rb + rowl;
#pragma unroll
      for (int t = 0; t < 4; ++t) {
        const int Jc = J + kq + t;
        As[kq + t][rowl] = (r < Ma && Jc < Ka) ? A[(size_t)r * lda + Jc] : 0.f;
      }
      const int Jr = J + kkb;
      float4 v = make_float4(0.f, 0.f, 0.f, 0.f);
      if (Jr < Ka) v = *(const float4*)(B + (size_t)Jr * N_DIM + cb + cc4);
      *(float4*)&Bs[kkb][cc4] = v;
    }
    __syncthreads();
#pragma unroll
    for (int kk = 0; kk < 16; ++kk) {
      const float4 a4 = *(const float4*)&As[kk][tm * 4];
      const float4 b4 = *(const float4*)&Bs[kk][tn * 4];
      acc[0][0] = fmaf(a4.x, b4.x, acc[0][0]);
      acc[0][1] = fmaf(a4.x, b4.y, acc[0][1]);
      acc[0][2] = fmaf(a4.x, b4.z, acc[0][2]);
      acc[0][3] = fmaf(a4.x, b4.w, acc[0][3]);
      acc[1][0] = fmaf(a4.y, b4.x, acc[1][0]);
      acc[1][1] = fmaf(a4.y, b4.y, acc[1][1]);
      acc[1][2] = fmaf(a4.y, b4.z, acc[1][2]);
      acc[1][3] = fmaf(a4.y, b4.w, acc[1][3]);
      acc[2][0] = fmaf(a4.z, b4.x, acc[2][0]);
      acc[2][1] = fmaf(a4.z, b4.y, acc[2][1]);
      acc[2][2] = fmaf(a4.z, b4.z, acc[2][2]);
      acc[2][3] = fmaf(a4.z, b4.w, acc[2][3]);
      acc[3][0] = fmaf(a4.w, b4.x, acc[3][0]);
      acc[3][1] = fmaf(a4.w, b4.y, acc[3][1]);
      acc[3][2] = fmaf(a4.w, b4.z, acc[3][2]);
      acc[3][3] = fmaf(a4.w, b4.w, acc[3][3]);
    }
    __syncthreads();
  }

#pragma unroll
  for (int i = 0; i < 4; ++i) {
    const int r = rb + tm * 4 + i;
    if (r < Ma) {
#pragma unroll
      for (int jj = 0; jj < 4; ++jj) {
        const int c = cb + tn * 4 + jj;
        out[(size_t)r * N_DIM + c] = C0[(size_t)r * N_DIM + c] - acc[i][jj];
      }
    }
  }
}

// =================== fp32 merge wrappers (k = 32, 64) ===================

__global__ __launch_bounds__(256)
void merge_ct_splitk(const float* __restrict__ WT, const float* __restrict__ UM,
                     float* __restrict__ Pt, int k, int SK) {
  const int tpm = (k + 63) >> 6;
  const int tiles = tpm * tpm;
  const int per_pair = tiles * SK;
  const int m = blockIdx.x / per_pair;
  const int rest = blockIdx.x % per_pair;
  const int sk = rest / tiles;
  const int t2 = rest % tiles;
  const int mb = (t2 / tpm) * 64;
  const int nb = (t2 % tpm) * 64;
  const int a0 = 2 * k * m, b0 = a0 + k;
  const int c0 = b0 & ~15;
  const int len = N_DIM - c0;
  const int step = ((len + SK - 1) / SK + 15) & ~15;
  int cbeg = c0 + sk * step;
  int cend = cbeg + step;
  if (cbeg > N_DIM) cbeg = N_DIM;
  if (cend > N_DIM) cend = N_DIM;
  const int mm = N_DIM / (2 * k);
  float* dst = Pt + (size_t)sk * mm * k * k + (size_t)m * k * k;
  nt_core(WT + (size_t)b0 * N_DIM, k, UM + (size_t)a0 * N_DIM, k,
          dst, k, mb, nb, cbeg, cend);
}

__global__ __launch_bounds__(256)
void ct_reduce(const float* __restrict__ Pt, float* __restrict__ Ct,
               int n, int SK) {
  const int i4 = (blockIdx.x * 256 + threadIdx.x) * 4;
  if (i4 >= n) return;
  float4 s = *(const float4*)(Pt + i4);
  for (int sk = 1; sk < SK; ++sk) {
    const float4 v = *(const float4*)(Pt + (size_t)sk * n + i4);
    s.x += v.x; s.y += v.y; s.z += v.z; s.w += v.w;
  }
  *(float4*)(Ct + i4) = s;
}

__global__ __launch_bounds__(256)
void merge_update_kernel(float* __restrict__ WT, const float* __restrict__ Ct,
                         int k) {
  const int tpr = (k + 63) >> 6;
  const int tiles = tpr * NT64;
  const int m = blockIdx.x / tiles;
  const int t = blockIdx.x % tiles;
  const int rb = (t / NT64) * 64;
  const int cb = (t % NT64) * 64;
  const int a0 = 2 * k * m, b0 = a0 + k;
  if (cb + 64 <= a0) return;
  nn_core(Ct + (size_t)m * k * k, k, k, k,
          WT + (size_t)a0 * N_DIM,
          WT + (size_t)b0 * N_DIM, WT + (size_t)b0 * N_DIM, rb, cb);
}

// =================== MFMA staging helpers ===================

__device__ __forceinline__ void stage_f32ld(const float* __restrict__ src,
                                            int rb, int kb, int t, int ld,
                                            ushort_t* __restrict__ Hd,
                                            ushort_t* __restrict__ Ld) {
  const int r0 = t >> 3;
  const int seg = (t & 7) * 4;
#pragma unroll
  for (int p = 0; p < 4; ++p) {
    const int row = r0 + p * 32;
    const float4 v = *(const float4*)(src + (size_t)(rb + row) * ld + kb + seg);
    const float f[4] = {v.x, v.y, v.z, v.w};
    ushort_t h[4], l[4];
#pragma unroll
    for (int q = 0; q < 4; ++q) {
      h[q] = f2bf_rtne(f[q]);
      l[q] = f2bf_rtne(f[q] - bf2f(h[q]));
    }
    const int o = row * 40 + seg;
    *(uint2*)(Hd + o) = make_uint2((unsigned)h[0] | ((unsigned)h[1] << 16),
                                   (unsigned)h[2] | ((unsigned)h[3] << 16));
    *(uint2*)(Ld + o) = make_uint2((unsigned)l[0] | ((unsigned)l[1] << 16),
                                   (unsigned)l[2] | ((unsigned)l[3] << 16));
  }
}

// B[J+kk][cb+n] (row-major ld N_DIM) -> Bs[n][kk] (transposed, stride 40)
__device__ __forceinline__ void stage_b_trans(const float* __restrict__ B,
                                              int J, int cb, int t,
                                              ushort_t* __restrict__ Hd,
                                              ushort_t* __restrict__ Ld) {
  const int kk8 = t >> 5;
  const int nq = (t & 31) * 4;
#pragma unroll
  for (int p = 0; p < 4; ++p) {
    const int kk = kk8 * 4 + p;
    const float4 v = *(const float4*)(B + (size_t)(J + kk) * N_DIM + cb + nq);
    const float f[4] = {v.x, v.y, v.z, v.w};
#pragma unroll
    for (int e = 0; e < 4; ++e) {
      const ushort_t h = f2bf_rtne(f[e]);
      Hd[(nq + e) * 40 + kk] = h;
      Ld[(nq + e) * 40 + kk] = f2bf_rtne(f[e] - bf2f(h));
    }
  }
}

__device__ __forceinline__ void stage_pre(const ushort_t* __restrict__ H,
                                          const ushort_t* __restrict__ L,
                                          int rb, int kb, int t,
                                          ushort_t* __restrict__ Hd,
                                          ushort_t* __restrict__ Ld) {
  const int r0 = t >> 1;
  const int seg = (t & 1) << 4;
  const size_t g = (size_t)(rb + r0) * N_DIM + kb + seg;
  const int o = r0 * 40 + seg;
  *(bf16x8*)(Hd + o) = *(const bf16x8*)(H + g);
  *(bf16x8*)(Hd + o + 8) = *(const bf16x8*)(H + g + 8);
  *(bf16x8*)(Ld + o) = *(const bf16x8*)(L + g);
  *(bf16x8*)(Ld + o + 8) = *(const bf16x8*)(L + g + 8);
}

// =================== MFMA merge kernels (k >= 128) ===================

// Ct[q][p] = sum_{c>=b0} WT[b0+q][c] * UM[a0+p][c]  (split-K partials)
__global__ __launch_bounds__(256)
void mct_mfma(const float* __restrict__ WT, const float* __restrict__ UM,
              float* __restrict__ dst, int k, int SK) {
  const int tpk = k >> 7;
  const int tiles = tpk * tpk;
  const int per_pair = tiles * SK;
  const int m = blockIdx.x / per_pair;
  const int rest = blockIdx.x % per_pair;
  const int sk = rest / tiles;
  const int t2 = rest % tiles;
  const int mb = (t2 / tpk) * 128;
  const int nb = (t2 % tpk) * 128;
  const int a0 = 2 * k * m, b0 = a0 + k;
  const int mm = N_DIM / (2 * k);
  const int len = N_DIM - b0;
  const int step = ((len + SK - 1) / SK + 31) & ~31;
  int cbeg = b0 + sk * step;
  int cend = cbeg + step;
  if (cbeg > N_DIM) cbeg = N_DIM;
  if (cend > N_DIM) cend = N_DIM;
  float* outp = dst + (size_t)sk * mm * k * k + (size_t)m * k * k;

  __shared__ ushort_t Ahs[128 * 40], Als[128 * 40], Bhs[128 * 40], Bls[128 * 40];
  const int t = threadIdx.x;
  const int l = t & 63, w = t >> 6;
  const int wm = w >> 1, wn = w & 1;
  const int lrow = l & 15, lk = l >> 4;

  f32x4 acc[4][4];
#pragma unroll
  for (int i = 0; i < 4; ++i)
#pragma unroll
    for (int j = 0; j < 4; ++j) {
      acc[i][j][0] = 0.f; acc[i][j][1] = 0.f;
      acc[i][j][2] = 0.f; acc[i][j][3] = 0.f;
    }

  for (int kb = cbeg; kb < cend; kb += 32) {
    __syncthreads();
    stage_f32ld(WT + (size_t)b0 * N_DIM, mb, kb, t, N_DIM, Ahs, Als);
    stage_f32ld(UM + (size_t)a0 * N_DIM, nb, kb, t, N_DIM, Bhs, Bls);
    __syncthreads();

    bf16x8 ah[4], al[4], bh[4], bl[4];
#pragma unroll
    for (int fm = 0; fm < 4; ++fm) {
      const int o = (wm * 64 + fm * 16 + lrow) * 40 + lk * 8;
      ah[fm] = *(const bf16x8*)(Ahs + o);
      al[fm] = *(const bf16x8*)(Als + o);
    }
#pragma unroll
    for (int fn = 0; fn < 4; ++fn) {
      const int o = (wn * 64 + fn * 16 + lrow) * 40 + lk * 8;
      bh[fn] = *(const bf16x8*)(Bhs + o);
      bl[fn] = *(const bf16x8*)(Bls + o);
    }
#pragma unroll
    for (int fm = 0; fm < 4; ++fm)
#pragma unroll
      for (int fn = 0; fn < 4; ++fn) {
        acc[fm][fn] = __builtin_amdgcn_mfma_f32_16x16x32_bf16(ah[fm], bh[fn], acc[fm][fn], 0, 0, 0);
        acc[fm][fn] = __builtin_amdgcn_mfma_f32_16x16x32_bf16(ah[fm], bl[fn], acc[fm][fn], 0, 0, 0);
        acc[fm][fn] = __builtin_amdgcn_mfma_f32_16x16x32_bf16(al[fm], bh[fn], acc[fm][fn], 0, 0, 0);
      }
  }

#pragma unroll
  for (int fm = 0; fm < 4; ++fm) {
    const int m0 = mb + wm * 64 + fm * 16 + lk * 4;
#pragma unroll
    for (int fn = 0; fn < 4; ++fn) {
      const int n = nb + wn * 64 + fn * 16 + lrow;
#pragma unroll
      for (int r = 0; r < 4; ++r)
        outp[(size_t)(m0 + r) * k + n] = acc[fm][fn][r];
    }
  }
}

// WT_b[q][c] -= sum_p Ct[q][p] * WT_a[p][c]   (in place)
__global__ __launch_bounds__(256)
void mupd_mfma(float* __restrict__ WT, const float* __restrict__ Ct, int k) {
  const int tpk = k >> 7;
  const int tiles = tpk * NT128;
  const int m = blockIdx.x / tiles;
  const int rest = blockIdx.x % tiles;
  const int rb = (rest / NT128) * 128;
  const int cb = (rest % NT128) * 128;
  const int a0 = 2 * k * m, b0 = a0 + k;
  if (cb + 128 <= a0) return;
  const float* A = Ct + (size_t)m * k * k;
  const float* Bw = WT + (size_t)a0 * N_DIM;
  float* C = WT + (size_t)b0 * N_DIM;

  __shared__ ushort_t Ahs[128 * 40], Als[128 * 40], Bhs[128 * 40], Bls[128 * 40];
  const int t = threadIdx.x;
  const int l = t & 63, w = t >> 6;
  const int wm = w >> 1, wn = w & 1;
  const int lrow = l & 15, lk = l >> 4;

  f32x4 acc[4][4];
#pragma unroll
  for (int i = 0; i < 4; ++i)
#pragma unroll
    for (int j = 0; j < 4; ++j) {
      acc[i][j][0] = 0.f; acc[i][j][1] = 0.f;
      acc[i][j][2] = 0.f; acc[i][j][3] = 0.f;
    }

  for (int J = 0; J < k; J += 32) {
    __syncthreads();
    stage_f32ld(A, rb, J, t, k, Ahs, Als);
    stage_b_trans(Bw, J, cb, t, Bhs, Bls);
    __syncthreads();

    bf16x8 ah[4], al[4], bh[4], bl[4];
#pragma unroll
    for (int fm = 0; fm < 4; ++fm) {
      const int o = (wm * 64 + fm * 16 + lrow) * 40 + lk * 8;
      ah[fm] = *(const bf16x8*)(Ahs + o);
      al[fm] = *(const bf16x8*)(Als + o);
    }
#pragma unroll
    for (int fn = 0; fn < 4; ++fn) {
      const int o = (wn * 64 + fn * 16 + lrow) * 40 + lk * 8;
      bh[fn] = *(const bf16x8*)(Bhs + o);
      bl[fn] = *(const bf16x8*)(Bls + o);
    }
#pragma unroll
    for (int fm = 0; fm < 4; ++fm)
#pragma unroll
      for (int fn = 0; fn < 4; ++fn) {
        acc[fm][fn] = __builtin_amdgcn_mfma_f32_16x16x32_bf16(ah[fm], bh[fn], acc[fm][fn], 0, 0, 0);
        acc[fm][fn] = __builtin_amdgcn_mfma_f32_16x16x32_bf16(ah[fm], bl[fn], acc[fm][fn], 0, 0, 0);
        acc[fm][fn] = __builtin_amdgcn_mfma_f32_16x16x32_bf16(al[fm], bh[fn], acc[fm][fn], 0, 0, 0);
      }
  }

#pragma unroll
  for (int fm = 0; fm < 4; ++fm) {
    const int m0 = rb + wm * 64 + fm * 16 + lk * 4;
#pragma unroll
    for (int fn = 0; fn < 4; ++fn) {
      const int n = cb + wn * 64 + fn * 16 + lrow;
#pragma unroll
      for (int r = 0; r < 4; ++r) {
        const size_t idx = (size_t)(m0 + r) * N_DIM + n;
        C[idx] = C[idx] - acc[fm][fn][r];
      }
    }
  }
}

// =================== conversions ===================

__global__ __launch_bounds__(256)
void trans_conv_kernel(const float* __restrict__ WT,
                       ushort_t* __restrict__ WTTh, ushort_t* __restrict__ WTTl) {
  __shared__ float Tt[64 * 65];
  const int t = threadIdx.x;
  const int bk = (blockIdx.x & 31) * 64;
  const int bn = (blockIdx.x >> 5) * 64;
  const int r = t >> 2;
  const int s = (t & 3) * 16;
#pragma unroll
  for (int q = 0; q < 4; ++q) {
    const float4 v = *(const float4*)(WT + (size_t)(bk + r) * N_DIM + bn + s + q * 4);
    Tt[r * 65 + s + q * 4 + 0] = v.x;
    Tt[r * 65 + s + q * 4 + 1] = v.y;
    Tt[r * 65 + s + q * 4 + 2] = v.z;
    Tt[r * 65 + s + q * 4 + 3] = v.w;
  }
  __syncthreads();
#pragma unroll
  for (int q = 0; q < 4; ++q) {
    float f[4];
    f[0] = Tt[(s + q * 4 + 0) * 65 + r];
    f[1] = Tt[(s + q * 4 + 1) * 65 + r];
    f[2] = Tt[(s + q * 4 + 2) * 65 + r];
    f[3] = Tt[(s + q * 4 + 3) * 65 + r];
    ushort_t h[4], l[4];
#pragma unroll
    for (int e = 0; e < 4; ++e) {
      h[e] = f2bf_rtne(f[e]);
      l[e] = f2bf_rtne(f[e] - bf2f(h[e]));
    }
    const size_t o = (size_t)(bn + r) * N_DIM + bk + s + q * 4;
    *(uint2*)(WTTh + o) = make_uint2((unsigned)h[0] | ((unsigned)h[1] << 16),
                                     (unsigned)h[2] | ((unsigned)h[3] << 16));
    *(uint2*)(WTTl + o) = make_uint2((unsigned)l[0] | ((unsigned)l[1] << 16),
                                     (unsigned)l[2] | ((unsigned)l[3] << 16));
  }
}

__global__ __launch_bounds__(256)
void um_conv_kernel(const float* __restrict__ UM,
                    ushort_t* __restrict__ UMh, ushort_t* __restrict__ UMl) {
  const size_t i4 = ((size_t)blockIdx.x * 256 + threadIdx.x) * 4;
  const float4 v = *(const float4*)(UM + i4);
  const float f[4] = {v.x, v.y, v.z, v.w};
  ushort_t h[4], l[4];
#pragma unroll
  for (int e = 0; e < 4; ++e) {
    h[e] = f2bf_rtne(f[e]);
    l[e] = f2bf_rtne(f[e] - bf2f(h[e]));
  }
  *(uint2*)(UMh + i4) = make_uint2((unsigned)h[0] | ((unsigned)h[1] << 16),
                                   (unsigned)h[2] | ((unsigned)h[3] << 16));
  *(uint2*)(UMl + i4) = make_uint2((unsigned)l[0] | ((unsigned)l[1] << 16),
                                   (unsigned)l[2] | ((unsigned)l[3] << 16));
}

// =================== MFMA application GEMMs ===================

template <int ASRC, int EP>
__global__ __launch_bounds__(256)
void gemm_bf_kernel(const float* __restrict__ Af,
                    const ushort_t* __restrict__ Ahg, const ushort_t* __restrict__ Alg,
                    const ushort_t* __restrict__ Bhg, const ushort_t* __restrict__ Blg,
                    const float* __restrict__ X, float* __restrict__ Cf,
                    ushort_t* __restrict__ Ch, ushort_t* __restrict__ Cl,
                    int tri) {
  __shared__ ushort_t Ahs[128 * 40], Als[128 * 40], Bhs[128 * 40], Bls[128 * 40];
  const int t = threadIdx.x;
  const int l = t & 63, w = t >> 6;
  const int wm = w >> 1, wn = w & 1;
  const int lrow = l & 15, lk = l >> 4;

  int bid = blockIdx.x;
  const int nwg = gridDim.x;
  if ((nwg & 7) == 0) {
    const int q = nwg >> 3;
    bid = (bid & 7) * q + (bid >> 3);
  }
  const int mb = (bid / NT128) * 128;
  const int nb = (bid % NT128) * 128;
  const int k0 = tri ? nb : 0;

  f32x4 acc[4][4];
#pragma unroll
  for (int i = 0; i < 4; ++i)
#pragma unroll
    for (int j = 0; j < 4; ++j) {
      acc[i][j][0] = 0.f; acc[i][j][1] = 0.f;
      acc[i][j][2] = 0.f; acc[i][j][3] = 0.f;
    }

  for (int kb = k0; kb < N_DIM; kb += 32) {
    __syncthreads();
    if (ASRC) stage_f32ld(Af, mb, kb, t, N_DIM, Ahs, Als);
    else      stage_pre(Ahg, Alg, mb, kb, t, Ahs, Als);
    stage_pre(Bhg, Blg, nb, kb, t, Bhs, Bls);
    __syncthreads();

    bf16x8 ah[4], al[4], bh[4], bl[4];
#pragma unroll
    for (int fm = 0; fm < 4; ++fm) {
      const int o = (wm * 64 + fm * 16 + lrow) * 40 + lk * 8;
      ah[fm] = *(const bf16x8*)(Ahs + o);
      al[fm] = *(const bf16x8*)(Als + o);
    }
#pragma unroll
    for (int fn = 0; fn < 4; ++fn) {
      const int o = (wn * 64 + fn * 16 + lrow) * 40 + lk * 8;
      bh[fn] = *(const bf16x8*)(Bhs + o);
      bl[fn] = *(const bf16x8*)(Bls + o);
    }
#pragma unroll
    for (int fm = 0; fm < 4; ++fm)
#pragma unroll
      for (int fn = 0; fn < 4; ++fn) {
        acc[fm][fn] = __builtin_amdgcn_mfma_f32_16x16x32_bf16(ah[fm], bh[fn], acc[fm][fn], 0, 0, 0);
        acc[fm][fn] = __builtin_amdgcn_mfma_f32_16x16x32_bf16(ah[fm], bl[fn], acc[fm][fn], 0, 0, 0);
        acc[fm][fn] = __builtin_amdgcn_mfma_f32_16x16x32_bf16(al[fm], bh[fn], acc[fm][fn], 0, 0, 0);
      }
  }

#pragma unroll
  for (int fm = 0; fm < 4; ++fm) {
    const int m0 = mb + wm * 64 + fm * 16 + lk * 4;
#pragma unroll
    for (int fn = 0; fn < 4; ++fn) {
      const int n = nb + wn * 64 + fn * 16 + lrow;
#pragma unroll
      for (int r = 0; r < 4; ++r) {
        const size_t idx = (size_t)(m0 + r) * N_DIM + n;
        const float f = acc[fm][fn][r];
        if (EP == 1) {
          Cf[idx] = X[idx] - f;
        } else {
          const ushort_t h = f2bf_rtne(f);
          Ch[idx] = h;
          Cl[idx] = f2bf_rtne(f - bf2f(h));
        }
      }
    }
  }
}

// =================== fallback sweep (round-2, proven) ===================

#define NRF 32
#define VCF 2
#define KGF 8
#define WPBF 4
#define NGRAMF ((KGF * (KGF + 1)) / 2)
#define NREDF (NGRAMF + KGF * VCF)

__device__ __forceinline__ void accum_group_f(const float (&u)[KGF],
                                              const float (&hr)[VCF],
                                              float (&red)[NREDF]) {
#pragma unroll
  for (int j = 0; j < KGF; ++j) {
#pragma unroll
    for (int l = 0; l <= j; ++l)
      red[(j * (j + 1)) / 2 + l] = fmaf(u[j], u[l], red[(j * (j + 1)) / 2 + l]);
#pragma unroll
    for (int c = 0; c < VCF; ++c)
      red[NGRAMF + j * VCF + c] = fmaf(u[j], hr[c], red[NGRAMF + j * VCF + c]);
  }
}

__global__ __launch_bounds__(256, 2)
void fallback_sweep_kernel(const float* __restrict__ x,
                           const float* __restrict__ w,
                           float* __restrict__ out) {
  const int lane = threadIdx.x & 63;
  const int wave = threadIdx.x >> 6;
  const int gw = blockIdx.x * WPBF + wave;
  const int col0 = gw * VCF;
  float h[NRF][VCF];
#pragma unroll
  for (int k = 0; k < NRF; ++k) {
    const int r = lane + 64 * k;
#pragma unroll
    for (int c = 0; c < VCF; ++c) h[k][c] = x[(size_t)(col0 + c) * N_DIM + r];
  }
  for (int i0 = N_DIM - KGF; i0 >= 0; i0 -= KGF) {
    const int ks = i0 >> 6;
    const float* wb = w + (size_t)i0 * N_DIM;
    float red[NREDF];
#pragma unroll
    for (int t = 0; t < NREDF; ++t) red[t] = 0.f;
#pragma unroll
    for (int k = 0; k < NRF; ++k) {
      const int r = lane + 64 * k;
      if (k > ks) {
        float u[KGF];
#pragma unroll
        for (int j = 0; j < KGF; ++j) u[j] = wb[(size_t)j * N_DIM + r];
        accum_group_f(u, h[k], red);
      } else if (k == ks) {
        float u[KGF];
#pragma unroll
        for (int j = 0; j < KGF; ++j) {
          float tt = wb[(size_t)j * N_DIM + r];
          u[j] = (r >= i0 + j) ? tt : 0.f;
        }
        if (i0 == N_DIM - KGF && r == N_DIM - 1) u[KGF - 1] = 1.0f;
        accum_group_f(u, h[k], red);
      }
    }
#pragma unroll
    for (int m = 1; m < 64; m <<= 1)
#pragma unroll
      for (int t = 0; t < NREDF; ++t) red[t] += __shfl_xor(red[t], m, 64);
    float beta[KGF];
#pragma unroll
    for (int j = 0; j < KGF; ++j) {
      const float n2 = red[(j * (j + 1)) / 2 + j];
      beta[j] = (n2 > 0.f) ? 2.0f / n2 : 0.f;
    }
    float T[KGF][KGF];
#pragma unroll
    for (int j = 0; j < KGF; ++j) {
      T[j][j] = beta[j];
#pragma unroll
      for (int r0 = 0; r0 < j; ++r0) {
        float acc = 0.f;
#pragma unroll
        for (int l = r0; l < j; ++l)
          acc = fmaf(T[r0][l], red[(j * (j + 1)) / 2 + l], acc);
        T[r0][j] = -beta[j] * acc;
      }
    }
    float z[KGF][VCF];
#pragma unroll
    for (int j = 0; j < KGF; ++j)
#pragma unroll
      for (int c = 0; c < VCF; ++c) {
        float acc = 0.f;
#pragma unroll
        for (int l = j; l < KGF; ++l)
          acc = fmaf(T[j][l], red[NGRAMF + l * VCF + c], acc);
        z[j][c] = acc;
      }
#pragma unroll
    for (int k = 0; k < NRF; ++k) {
      const int r = lane + 64 * k;
      if (k >= ks) {
        float u[KGF];
#pragma unroll
        for (int j = 0; j < KGF; ++j) {
          float tt = wb[(size_t)j * N_DIM + r];
          u[j] = (k > ks || r >= i0 + j) ? tt : 0.f;
        }
        if (i0 == N_DIM - KGF && r == N_DIM - 1) u[KGF - 1] = 1.0f;
#pragma unroll
        for (int c = 0; c < VCF; ++c) {
          float acc = h[k][c];
#pragma unroll
          for (int j = 0; j < KGF; ++j) acc = fmaf(-u[j], z[j][c], acc);
          h[k][c] = acc;
        }
      }
    }
  }
#pragma unroll
  for (int k = 0; k < NRF; ++k) {
    const int r = lane + 64 * k;
#pragma unroll
    for (int c = 0; c < VCF; ++c)
      out[(size_t)(col0 + c) * N_DIM + r] = h[k][c];
  }
}

// =================== launch ===================

extern "C" void kernel_launch(void* const* d_in, const int* in_sizes, int n_in,
                              void* d_out, int out_size, void* d_ws, size_t ws_size,
                              hipStream_t stream) {
  const float* x = (const float*)d_in[0];
  const float* w = (const float*)d_in[1];
  float* out = (float*)d_out;
  const int Bsz = in_sizes[0] / N_DIM;      // 4096

  const size_t NW = (size_t)N_DIM * N_DIM;  // 4M floats
  float* ws = (float*)d_ws;

  float* WT = ws;                                   // [0, 4M)
  float* UM = ws + NW;                              // [4M, 8M)
  ushort_t* WTTh = (ushort_t*)(ws + 2 * NW);        // [8M,10M) floats-worth
  ushort_t* WTTl = WTTh + NW;                       // [10M,12M)
  float* Ct = ws + 3 * NW;                          // [12M,13M)
  float* Pt = ws + 3 * NW + NW / 4;                 // [13M,14M)
  float* Pg = Ct;                                   // base phase: 512K floats
  float* Tg = Pt;                                   // base phase: 64K floats
  ushort_t* UMh = (ushort_t*)(ws + 3 * NW);         // [12M,14M) (after merges)
  ushort_t* UMl = UMh + NW;                         // [14M,16M)
  ushort_t* A1h = (ushort_t*)ws;                    // [0,4M)  (after trans_conv)
  ushort_t* A1l = (ushort_t*)(ws + NW);             // [4M,8M) (after um_conv)

  const size_t need = 4 * NW * sizeof(float);       // 64 MB

  if (ws_size < need || (Bsz % 128) != 0) {
    fallback_sweep_kernel<<<Bsz / (VCF * WPBF), 256, 0, stream>>>(x, w, out);
    return;
  }

  prep_kernel<<<(int)(NW / 1024), 256, 0, stream>>>(w, UM);

  // base-32 WY build (parallel)
  gram32_partial<<<64 * 8, 256, 0, stream>>>(UM, Pg);
  t32_kernel<<<64, 256, 0, stream>>>(Pg, Tg);
  wt32_kernel<<<64 * 16, 256, 0, stream>>>(UM, Tg, WT);

  // merge ladder
  for (int k = 32; k <= N_DIM / 2; k <<= 1) {
    const int mm = N_DIM / (2 * k);
    if (k < 128) {
      const int tpm = (k + 63) >> 6;
      const int tiles = tpm * tpm;
      int SK = 256 / (mm * tiles);
      if (SK < 1) SK = 1;
      if (SK > 16) SK = 16;
      float* dst = (SK == 1) ? Ct : Pt;
      merge_ct_splitk<<<mm * tiles * SK, 256, 0, stream>>>(WT, UM, dst, k, SK);
      if (SK > 1) {
        const int n = mm * k * k;
        ct_reduce<<<(n + 1023) / 1024, 256, 0, stream>>>(Pt, Ct, n, SK);
      }
      merge_update_kernel<<<mm * tpm * NT64, 256, 0, stream>>>(WT, Ct, k);
    } else {
      const int tpk = k >> 7;
      const int tiles = tpk * tpk;
      const int SK = (k == 128) ? 8 : (k == 256) ? 4 : (k == 512) ? 2 : 1;
      float* dst = (SK == 1) ? Ct : Pt;
      mct_mfma<<<mm * tiles * SK, 256, 0, stream>>>(WT, UM, dst, k, SK);
      if (SK > 1) {
        const int n = mm * k * k;
        ct_reduce<<<(n + 1023) / 1024, 256, 0, stream>>>(Pt, Ct, n, SK);
      }
      mupd_mfma<<<mm * tpk * NT128, 256, 0, stream>>>(WT, Ct, k);
    }
  }

  trans_conv_kernel<<<1024, 256, 0, stream>>>(WT, WTTh, WTTl);
  um_conv_kernel<<<(int)(NW / 1024), 256, 0, stream>>>(UM, UMh, UMl);

  const int grid = (Bsz / 128) * NT128;     // 512
  gemm_bf_kernel<1, 2><<<grid, 256, 0, stream>>>(
      x, nullptr, nullptr, UMh, UMl, nullptr, nullptr, A1h, A1l, 1);
  gemm_bf_kernel<0, 1><<<grid, 256, 0, stream>>>(
      nullptr, A1h, A1l, WTTh, WTTl, x, out, nullptr, nullptr, 0);
}